// Round 1
// 243.810 us; speedup vs baseline: 1.0325x; 1.0325x over previous
//
#include <hip/hip_runtime.h>
#include <math.h>

#define BB   2
#define CC   256
#define NPT  4096
#define HH   4
#define DD   64
#define KNN  16
#define EPSBN 1e-5f

typedef __attribute__((ext_vector_type(8))) short short8;
typedef __attribute__((ext_vector_type(4))) float f32x4;

typedef __attribute__((address_space(3))) unsigned int lds_u32;
typedef const __attribute__((address_space(1))) unsigned int glb_u32;
__device__ __forceinline__ void gl_lds16(const void* g, void* l) {
  __builtin_amdgcn_global_load_lds((glb_u32*)g, (lds_u32*)l, 16, 0, 0);
}

__device__ __forceinline__ unsigned short f2b(float f) {
  union { float f; unsigned int u; } v; v.f = f;
  unsigned int r = (v.u + 0x7FFFu + ((v.u >> 16) & 1u)) >> 16;
  return (unsigned short)r;
}
__device__ __forceinline__ void up2(unsigned int u, float& a, float& b) {
  union { unsigned int x; float f; } lo, hi;
  lo.x = u << 16; hi.x = u & 0xffff0000u;
  a = lo.f; b = hi.f;
}
__device__ __forceinline__ void up16(uint4 u0, uint4 u1, float* f) {
  up2(u0.x, f[0], f[1]);  up2(u0.y, f[2], f[3]);
  up2(u0.z, f[4], f[5]);  up2(u0.w, f[6], f[7]);
  up2(u1.x, f[8], f[9]);  up2(u1.y, f[10], f[11]);
  up2(u1.z, f[12], f[13]); up2(u1.w, f[14], f[15]);
}

// v_med3_u32: 1-op sorted-list insert step (no builtin on gfx950 -> inline asm)
__device__ __forceinline__ unsigned int med3u(unsigned int a, unsigned int b, unsigned int c) {
  unsigned int d;
  asm("v_med3_u32 %0, %1, %2, %3" : "=v"(d) : "v"(a), "v"(b), "v"(c));
  return d;
}

// ================= stage 1 bodies (independent work, fused dispatch) =================
__device__ __forceinline__
void wcast_body(const float* Wq, const float* Wkv, const float* Wp,
                const float* W1, const float* W2,
                unsigned short* oQKV, unsigned short* oP,
                unsigned short* o1, unsigned short* o2,
                const float* rp_w1, const float* rp_g, const float* rp_b,
                const float* rp_m, const float* rp_v, const float* rp_w2,
                float4* w1f, float4* W2t, int blk) {
  if (blk == 3072) {            // prep: fold rp BN into w1, reduce rp_w2 over heads
    int c = threadIdx.x;
    float s  = rp_g[c] / sqrtf(rp_v[c] + EPSBN);
    float b0 = rp_b[c] - rp_m[c] * s;
    w1f[c] = make_float4(rp_w1[c*3+0]*s, rp_w1[c*3+1]*s, rp_w1[c*3+2]*s, b0);
    float a0=0.f,a1=0.f,a2=0.f,a3=0.f;
    for (int o = 0; o < 64; o++) {
      a0 += rp_w2[(      o)*CC + c];
      a1 += rp_w2[( 64 + o)*CC + c];
      a2 += rp_w2[(128 + o)*CC + c];
      a3 += rp_w2[(192 + o)*CC + c];
    }
    W2t[c] = make_float4(a0,a1,a2,a3);
    return;
  }
  int i = blk * 256 + threadIdx.x;          // 786432 total
  if (i < 65536)        oQKV[i] = f2b(Wq[i]);
  else if (i < 196608)  oQKV[i] = f2b(Wkv[i - 65536]);
  else if (i < 262144)  oP[i - 196608] = f2b(Wp[i - 196608]);
  else if (i < 524288)  o1[i - 262144] = f2b(W1[i - 262144]);
  else                  o2[i - 524288] = f2b(W2[i - 524288]);
}

__device__ __forceinline__
void xcast_body(const float* x, unsigned short* xb, float* xf,
                float (*T)[65], int bx, int by, int bz) {
  int n0 = bx * 64, c0 = by * 64, bb = bz;
  int tid = threadIdx.x;
  {
    int crow = tid >> 2, ns = (tid & 3) * 16;
    const float* xp = x + ((size_t)(bb*CC + c0 + crow))*NPT + n0 + ns;
#pragma unroll
    for (int i = 0; i < 4; i++) {
      float4 v = ((const float4*)xp)[i];
      T[crow][ns + i*4 + 0] = v.x; T[crow][ns + i*4 + 1] = v.y;
      T[crow][ns + i*4 + 2] = v.z; T[crow][ns + i*4 + 3] = v.w;
    }
  }
  __syncthreads();
  {
    int nrow = tid >> 2, cs = (tid & 3) * 16;
    float vals[16];
#pragma unroll
    for (int i = 0; i < 16; i++) vals[i] = T[cs + i][nrow];
    size_t orow = ((size_t)(bb*NPT + n0 + nrow))*CC + c0 + cs;
#pragma unroll
    for (int i = 0; i < 4; i++)
      *(float4*)&xf[orow + i*4] = make_float4(vals[i*4], vals[i*4+1], vals[i*4+2], vals[i*4+3]);
    unsigned short us[16];
#pragma unroll
    for (int i = 0; i < 16; i++) us[i] = f2b(vals[i]);
    *(uint4*)&xb[orow]     = *(const uint4*)&us[0];
    *(uint4*)&xb[orow + 8] = *(const uint4*)&us[8];
  }
}

// KNN stage 1: packed-u32 sorted-insert via v_med3_u32 — 1 op/position instead of
// the 2-op min/max MSTEP pair. Insertion into an ascending list k0..k15:
//   k_i' = med3(key, k_{i-1}, k_i)   (applied DESCENDING so old k_{i-1} is read)
//   k0'  = min(key, k0)
// key below both -> shifts old k_{i-1} up; between -> key lands; above -> unchanged.
// Keys are (non-negative float bits & ~0x1FF) | in-segment index, so u32 order ==
// (distance, index) order and sentinels 0xFFFFFFFF sort last.
#define MPROC(M4, MI) { \
    float nd = fmaf(qx2, (M4).x, fmaf(qy2, (M4).y, fmaf(qz2, (M4).z, (M4).w + qsq))); \
    nd = fmaxf(nd, 0.f); \
    unsigned int key = (__float_as_uint(nd) & 0xFFFFFE00u) | (unsigned int)(MI); \
    k15 = med3u(key, k14, k15); k14 = med3u(key, k13, k14); \
    k13 = med3u(key, k12, k13); k12 = med3u(key, k11, k12); \
    k11 = med3u(key, k10, k11); k10 = med3u(key, k9,  k10); \
    k9  = med3u(key, k8,  k9 ); k8  = med3u(key, k7,  k8 ); \
    k7  = med3u(key, k6,  k7 ); k6  = med3u(key, k5,  k6 ); \
    k5  = med3u(key, k4,  k5 ); k4  = med3u(key, k3,  k4 ); \
    k3  = med3u(key, k2,  k3 ); k2  = med3u(key, k1,  k2 ); \
    k1  = med3u(key, k0,  k1 ); k0  = min(key, k0); }

// Each block stages 2 x 512-pt segments (sp[1024]); wave wv takes a 256-candidate
// half (seg = wv>>1, half = wv&1) so in-segment index still fits 9 bits.
// 16 partial lists/query (was 32) -> Pp halves to 16 MB.
__device__ __forceinline__
void knn_partial_body(const float* xyz, float4* Pp, float4* sp, int s2, int qg, int b) {
  const float* base = xyz + (size_t)b * 3 * NPT;
  int c0 = s2 * 1024;
  for (int i = threadIdx.x; i < 1024; i += 256) {
    float mx = base[c0 + i], my = base[NPT + c0 + i], mz = base[2*NPT + c0 + i];
    sp[i] = make_float4(mx, my, mz, mx*mx + my*my + mz*mz);
  }
  int lane = threadIdx.x & 63;
  int wv   = threadIdx.x >> 6;
  int qn   = qg * 64 + lane;
  float qx = base[qn], qy = base[NPT + qn], qz = base[2*NPT + qn];
  float qsq = qx*qx + qy*qy + qz*qz;
  float qx2 = -2.f*qx, qy2 = -2.f*qy, qz2 = -2.f*qz;
  __syncthreads();

  unsigned int k0=0xFFFFFFFFu,k1=0xFFFFFFFFu,k2=0xFFFFFFFFu,k3=0xFFFFFFFFu,
               k4=0xFFFFFFFFu,k5=0xFFFFFFFFu,k6=0xFFFFFFFFu,k7=0xFFFFFFFFu,
               k8=0xFFFFFFFFu,k9=0xFFFFFFFFu,k10=0xFFFFFFFFu,k11=0xFFFFFFFFu,
               k12=0xFFFFFFFFu,k13=0xFFFFFFFFu,k14=0xFFFFFFFFu,k15=0xFFFFFFFFu;

  int sb = wv * 256;            // sp offset: seg*512 + half*256
  int ib = (wv & 1) * 256;      // in-segment index base (9-bit payload)
  for (int mm = 0; mm < 256; mm += 4) {
    float4 a = sp[sb+mm], bq = sp[sb+mm+1], cq = sp[sb+mm+2], dq = sp[sb+mm+3];
    MPROC(a,  ib+mm)
    MPROC(bq, ib+mm+1)
    MPROC(cq, ib+mm+2)
    MPROC(dq, ib+mm+3)
  }

  int cadd = c0 + (wv >> 1) * 512;      // global index = cadd + 9-bit payload
  int gq = b * NPT + qn;
  float4* out = Pp + (size_t)gq * 128 + (s2*4 + wv)*8;
#define UNP(K) __uint_as_float(K & 0xFFFFFE00u), __int_as_float(cadd + (int)(K & 0x1FFu))
  out[0] = make_float4(UNP(k0),  UNP(k1));
  out[1] = make_float4(UNP(k2),  UNP(k3));
  out[2] = make_float4(UNP(k4),  UNP(k5));
  out[3] = make_float4(UNP(k6),  UNP(k7));
  out[4] = make_float4(UNP(k8),  UNP(k9));
  out[5] = make_float4(UNP(k10), UNP(k11));
  out[6] = make_float4(UNP(k12), UNP(k13));
  out[7] = make_float4(UNP(k14), UNP(k15));
#undef UNP
}

// stage1 fused dispatch: [0,512) xcast | [512,3585) wcast | [3585,4097) knn_partial.
// LDS union: xcast's 64x65 transpose tile and knn's sp[1024] share one 16.6 KB pool
// (was 24.8 KB summed) -> 8 blocks/CU headroom.
__global__ __launch_bounds__(256) __attribute__((amdgpu_waves_per_eu(1, 4)))
void stage1_kernel(const float* x, unsigned short* xb, float* xf,
                   const float* xyz, float4* Pp,
                   const float* Wq, const float* Wkv, const float* Wp,
                   const float* W1, const float* W2,
                   unsigned short* oQKV, unsigned short* oP,
                   unsigned short* o1, unsigned short* o2,
                   const float* rp_w1, const float* rp_g, const float* rp_b,
                   const float* rp_m, const float* rp_v, const float* rp_w2,
                   float4* w1f, float4* W2t) {
  __shared__ __align__(16) char smem[64*65*4];
  int bi = blockIdx.x;
  if (bi < 512) {
    xcast_body(x, xb, xf, (float(*)[65])smem, bi & 63, (bi >> 6) & 3, bi >> 8);
  } else if (bi < 3585) {
    wcast_body(Wq, Wkv, Wp, W1, W2, oQKV, oP, o1, o2,
               rp_w1, rp_g, rp_b, rp_m, rp_v, rp_w2, w1f, W2t, bi - 512);
  } else {
    int i = bi - 3585;
    knn_partial_body(xyz, Pp, (float4*)smem, i & 3, (i >> 2) & 63, i >> 8);
  }
}

// ================= stage 2: knn_merge + qkv GEMM (independent, fused) ================
__device__ __forceinline__
void knn_merge_body(const float4* Pp, int* idx_out, int blk) {
  int wv   = threadIdx.x >> 6;
  int lane = threadIdx.x & 63;
  int gq   = blk * 4 + wv;
  float d[4]; int ii[4];
  const float4* base = Pp + (size_t)gq * 128;
#pragma unroll
  for (int j = 0; j < 2; j++) {
    float4 v = base[j*64 + lane];
    d[2*j+0] = v.x; ii[2*j+0] = __float_as_int(v.y);
    d[2*j+1] = v.z; ii[2*j+1] = __float_as_int(v.w);
  }
  for (int sel = 0; sel < 16; sel++) {
    float bd = 3.5e38f; int bi = 0x7fffffff;
#pragma unroll
    for (int t = 0; t < 4; t++) {
      bool better = (d[t] < bd) || (d[t] == bd && ii[t] < bi);
      if (better) { bd = d[t]; bi = ii[t]; }
    }
#pragma unroll
    for (int off = 1; off < 64; off <<= 1) {
      float od = __shfl_xor(bd, off, 64);
      int   oi = __shfl_xor(bi, off, 64);
      if (od < bd || (od == bd && oi < bi)) { bd = od; bi = oi; }
    }
#pragma unroll
    for (int t = 0; t < 4; t++)
      if (ii[t] == bi) d[t] = 3.5e38f;
    if (lane == 0) idx_out[gq*16 + sel] = bi;
  }
}

// ------- MFMA bf16 GEMM v3: NT-templated N-tile (NT*64 rows) ------------------------
struct MG {
  const unsigned short* A; const unsigned short* Wt; int K; int M;
  unsigned short* OutB; float* OutF;
  const float* bias; const float* resid;
  const float* bng; const float* bnb; const float* bnm; const float* bnv;
};

template<int EPI, int NT>
__device__ __forceinline__ void mgemm_body(const MG& p, int bx, int by, int bz) {
  __shared__ unsigned short As[NT*64*64];
  __shared__ unsigned short Bs[64*64];
  const int tid  = threadIdx.x;
  const int bb   = bz;
  const int n0   = bx * (NT*64);
  const int m0   = by * 64;
  const int lane = tid & 63;
  const int wv   = tid >> 6;
  const int l15  = lane & 15;
  const int quad = lane >> 4;
  const int K    = p.K;
  const int WR   = NT*16;                   // wave row span

  f32x4 acc[NT][4];
#pragma unroll
  for (int i = 0; i < NT; i++)
#pragma unroll
    for (int j = 0; j < 4; j++) acc[i][j] = (f32x4){0.f, 0.f, 0.f, 0.f};

  const int srow = wv*8 + (lane >> 3);
  const int pseg = lane & 7;
  const unsigned short* Abase = p.A  + (size_t)bb*NPT*K;

  for (int c0 = 0; c0 < K; c0 += 64) {
#pragma unroll
    for (int t = 0; t < NT*2; t++) {
      int row = t*32 + srow;
      int ls  = pseg ^ (row & 7);
      gl_lds16(Abase + (size_t)(n0 + row)*K + c0 + ls*8,
               &As[wv*512 + t*2048 + lane*8]);
    }
#pragma unroll
    for (int t = 0; t < 2; t++) {
      int row = t*32 + srow;
      int ls  = pseg ^ (row & 7);
      gl_lds16(p.Wt + (size_t)(m0 + row)*K + c0 + ls*8,
               &Bs[wv*512 + t*2048 + lane*8]);
    }
    __syncthreads();
    short8 bf[4][2];
#pragma unroll
    for (int mt = 0; mt < 4; mt++)
#pragma unroll
      for (int kk = 0; kk < 2; kk++) {
        int row = mt*16 + l15;
        int ps  = (kk*4 + quad) ^ (row & 7);
        bf[mt][kk] = *(const short8*)&Bs[row*64 + ps*8];
      }
#pragma unroll
    for (int nt = 0; nt < NT; nt++)
#pragma unroll
      for (int kk = 0; kk < 2; kk++) {
        int row = wv*WR + nt*16 + l15;
        int ps  = (kk*4 + quad) ^ (row & 7);
        short8 af = *(const short8*)&As[row*64 + ps*8];
#pragma unroll
        for (int mt = 0; mt < 4; mt++)
          acc[nt][mt] = __builtin_amdgcn_mfma_f32_16x16x32_bf16(af, bf[mt][kk], acc[nt][mt], 0, 0, 0);
      }
    __syncthreads();
  }

  if (EPI == 0 || EPI == 1) {
    float bs[4];
#pragma unroll
    for (int mt = 0; mt < 4; mt++)
      bs[mt] = (EPI == 1) ? p.bias[m0 + mt*16 + l15] : 0.f;
#pragma unroll
    for (int nt = 0; nt < NT; nt++)
#pragma unroll
      for (int reg = 0; reg < 4; reg++) {
        size_t row = ((size_t)(bb*NPT + n0 + wv*WR + nt*16 + quad*4 + reg))*p.M + m0;
#pragma unroll
        for (int mt = 0; mt < 4; mt++) {
          float v = acc[nt][mt][reg] + bs[mt];
          if (EPI == 1) v = fmaxf(v, 0.f);
          p.OutB[row + mt*16 + l15] = f2b(v);
        }
      }
  } else if (EPI == 2) {
    float sc[4], sh[4];
#pragma unroll
    for (int mt = 0; mt < 4; mt++) {
      int m = m0 + mt*16 + l15;
      float s = p.bng[m] / sqrtf(p.bnv[m] + EPSBN);
      sc[mt] = s; sh[mt] = p.bnb[m] - p.bnm[m]*s;
    }
#pragma unroll
    for (int nt = 0; nt < NT; nt++)
#pragma unroll
      for (int reg = 0; reg < 4; reg++) {
        size_t row = ((size_t)(bb*NPT + n0 + wv*WR + nt*16 + quad*4 + reg))*p.M + m0;
#pragma unroll
        for (int mt = 0; mt < 4; mt++) {
          float r = p.resid[row + mt*16 + l15];
          float v = (acc[nt][mt][reg] + r)*sc[mt] + sh[mt];
          p.OutF[row + mt*16 + l15] = v;
          p.OutB[row + mt*16 + l15] = f2b(v);
        }
      }
  } else {  // EPI == 3
    __shared__ float Tb[4][4][16*17];
    float sc[4], sh[4], bs[4];
#pragma unroll
    for (int mt = 0; mt < 4; mt++) {
      int m = m0 + mt*16 + l15;
      float s = p.bng[m] / sqrtf(p.bnv[m] + EPSBN);
      sc[mt] = s; sh[mt] = p.bnb[m] - p.bnm[m]*s;
      bs[mt] = p.bias[m];
    }
#pragma unroll
    for (int nt = 0; nt < NT; nt++) {
#pragma unroll
      for (int reg = 0; reg < 4; reg++) {
        size_t row = ((size_t)(bb*NPT + n0 + wv*WR + nt*16 + quad*4 + reg))*p.M + m0;
#pragma unroll
        for (int mt = 0; mt < 4; mt++) {
          float r = p.resid[row + mt*16 + l15];
          float v = (acc[nt][mt][reg] + bs[mt] + r)*sc[mt] + sh[mt];
          Tb[wv][mt][(quad*4 + reg)*17 + l15] = v;
        }
      }
      __syncthreads();
#pragma unroll
      for (int mt = 0; mt < 4; mt++)
#pragma unroll
        for (int reg = 0; reg < 4; reg++) {
          float v = Tb[wv][mt][l15*17 + quad*4 + reg];
          p.OutF[((size_t)(bb*p.M + m0 + mt*16 + quad*4 + reg))*NPT
                 + n0 + wv*WR + nt*16 + l15] = v;
        }
      __syncthreads();
    }
  }
}

template<int EPI, int NT>
__global__ __launch_bounds__(256)
void mgemm_kernel(MG p) { mgemm_body<EPI, NT>(p, blockIdx.x, blockIdx.y, blockIdx.z); }

// stage2 fused: [0,2048) knn_merge | [2048,2816) qkv GEMM (grid 32x12x2 linearized)
__global__ __launch_bounds__(256)
void stage2_kernel(const float4* Pp, int* idx, MG pqkv) {
  int bi = blockIdx.x;
  if (bi < 2048) {
    knn_merge_body(Pp, idx, bi);
  } else {
    int i = bi - 2048;
    mgemm_body<0, 2>(pqkv, i & 31, (i >> 5) % 12, i / 384);
  }
}

// ---------------- fused attention v4: 4 points/block, shared weight reads ----------
__global__ __launch_bounds__(256, 4)
void attn_kernel(const unsigned short* __restrict__ qkv, const float4* __restrict__ w1f,
                 const float4* __restrict__ W2t, const float* __restrict__ xyz,
                 const int* __restrict__ idx, unsigned short* __restrict__ attn_b) {
  __shared__ float4 sw1[256];
  __shared__ float4 sw2[256];
  __shared__ int   sidx[4][16];
  __shared__ float srel[4][16][4];
  __shared__ float sbias[4][16][4];
  __shared__ float red[4][16*68];
  int tid = threadIdx.x;
  int bn0 = blockIdx.x * 4;
  int b   = bn0 >> 12;
  sw1[tid] = w1f[tid];
  sw2[tid] = W2t[tid];
  if (tid < 64) {
    int p = tid >> 4, kk = tid & 15;
    int bn = bn0 + p, n = bn & 4095;
    int j = idx[bn*16 + kk];
    sidx[p][kk] = j;
    const float* pb = xyz + (size_t)b * 3 * NPT;
    srel[p][kk][0] = pb[j]         - pb[n];
    srel[p][kk][1] = pb[NPT + j]   - pb[NPT + n];
    srel[p][kk][2] = pb[2*NPT + j] - pb[2*NPT + n];
  }
  __syncthreads();
  {  // ---- bias phase: 4 points per weight read ----
    int kk = tid >> 4, cs = tid & 15;
    float rx[4], ry[4], rz[4], h[4][4];
#pragma unroll
    for (int p = 0; p < 4; p++) {
      rx[p] = srel[p][kk][0]; ry[p] = srel[p][kk][1]; rz[p] = srel[p][kk][2];
#pragma unroll
      for (int q = 0; q < 4; q++) h[p][q] = 0.f;
    }
#pragma unroll
    for (int i = 0; i < 16; i++) {
      int c = cs*16 + ((i + cs) & 15);
      float4 w  = sw1[c];
      float4 w2 = sw2[c];
#pragma unroll
      for (int p = 0; p < 4; p++) {
        float t0 = fmaxf(fmaf(rx[p], w.x, fmaf(ry[p], w.y, fmaf(rz[p], w.z, w.w))), 0.f);
        h[p][0] = fmaf(t0, w2.x, h[p][0]); h[p][1] = fmaf(t0, w2.y, h[p][1]);
        h[p][2] = fmaf(t0, w2.z, h[p][2]); h[p][3] = fmaf(t0, w2.w, h[p][3]);
      }
    }
#pragma unroll
    for (int off = 1; off < 16; off <<= 1)
#pragma unroll
      for (int p = 0; p < 4; p++)
#pragma unroll
        for (int q = 0; q < 4; q++)
          h[p][q] += __shfl_xor(h[p][q], off, 64);
    if (cs == 0)
#pragma unroll
      for (int p = 0; p < 4; p++)
#pragma unroll
        for (int q = 0; q < 4; q++) sbias[p][kk][q] = h[p][q];
  }
  __syncthreads();
  // ---- attention phase: 4 points serial ----
  int wv   = tid >> 6;
  int lane = tid & 63;
  int k    = lane >> 2;
  int c4   = lane & 3;
  int ch0  = wv*64 + c4*16;
  size_t base = (size_t)(b*NPT) * 768;
#pragma unroll 1
  for (int p = 0; p < 4; p++) {
    int bn = bn0 + p;
    size_t rowq = (size_t)bn * 768;
    float qf[16];
    {
      uint4 q0 = *(const uint4*)(qkv + rowq + ch0);
      uint4 q1 = *(const uint4*)(qkv + rowq + ch0 + 8);
      up16(q0, q1, qf);
    }
    int j = sidx[p][k];
    float dot = 0.f;
    {
      const unsigned short* krow = qkv + base + (size_t)j*768 + 256 + ch0;
      uint4 k0 = *(const uint4*)(krow);
      uint4 k1 = *(const uint4*)(krow + 8);
      float kf[16];
      up16(k0, k1, kf);
#pragma unroll
      for (int i = 0; i < 16; i++) dot = fmaf(qf[i], kf[i], dot);
    }
    dot += __shfl_xor(dot, 1, 64);
    dot += __shfl_xor(dot, 2, 64);
    float logit = dot * 0.125f + sbias[p][k][wv];
    float mx = logit;
#pragma unroll
    for (int off = 4; off < 64; off <<= 1) mx = fmaxf(mx, __shfl_xor(mx, off, 64));
    float e = __expf(logit - mx);
    float ssum = e;
#pragma unroll
    for (int off = 4; off < 64; off <<= 1) ssum += __shfl_xor(ssum, off, 64);
    float w = e / ssum;
    {
      const unsigned short* vrow = qkv + base + (size_t)j*768 + 512 + ch0;
      uint4 v0 = *(const uint4*)(vrow);
      uint4 v1 = *(const uint4*)(vrow + 8);
      float vf[16];
      up16(v0, v1, vf);
      float* dst = &red[wv][k*68 + c4*16];
#pragma unroll
      for (int g = 0; g < 4; g++)
        ((float4*)dst)[g] = make_float4(w*vf[g*4], w*vf[g*4+1], w*vf[g*4+2], w*vf[g*4+3]);
    }
    __syncthreads();
    float o = 0.f;
#pragma unroll
    for (int kk2 = 0; kk2 < 16; kk2++) o += red[wv][kk2*68 + lane];
    attn_b[(size_t)bn*256 + wv*64 + lane] = f2b(o);
    __syncthreads();
  }
}

extern "C" void kernel_launch(void* const* d_in, const int* in_sizes, int n_in,
                              void* d_out, int out_size, void* d_ws, size_t ws_size,
                              hipStream_t stream) {
  const float* x     = (const float*)d_in[0];
  const float* xyz   = (const float*)d_in[1];
  const float* Wq    = (const float*)d_in[2];
  const float* Wkv   = (const float*)d_in[3];
  const float* Wproj = (const float*)d_in[4];
  const float* rp_w1 = (const float*)d_in[5];
  const float* rp_g  = (const float*)d_in[6];
  const float* rp_b  = (const float*)d_in[7];
  const float* rp_m  = (const float*)d_in[8];
  const float* rp_v  = (const float*)d_in[9];
  const float* rp_w2 = (const float*)d_in[10];
  const float* bn1_g = (const float*)d_in[11];
  const float* bn1_b = (const float*)d_in[12];
  const float* bn1_m = (const float*)d_in[13];
  const float* bn1_v = (const float*)d_in[14];
  const float* bn2_g = (const float*)d_in[15];
  const float* bn2_b = (const float*)d_in[16];
  const float* bn2_m = (const float*)d_in[17];
  const float* bn2_v = (const float*)d_in[18];
  const float* ffn_w1 = (const float*)d_in[19];
  const float* ffn_b1 = (const float*)d_in[20];
  const float* ffn_w2 = (const float*)d_in[21];
  const float* ffn_b2 = (const float*)d_in[22];

  char* ws = (char*)d_ws;
  // static region
  float4* w1f = (float4*)(ws + 0);                         //   4 KB
  float4* W2t = (float4*)(ws + 4096);                      //   4 KB
  int*    idx = (int*)  (ws + 8192);                       // 512 KB
  // reuse region A (32 MB): KNN scratch first, then post-attn tensors
  const size_t oA = 532480;
  float4*         Pp     = (float4*)(ws + oA);             // 16 MB [B*N][128] (d,idx)
  unsigned short* attn_b = (unsigned short*)(ws + oA);                 //  4 MB bf16 [B][N][256]
  float*          x1f    = (float*)(ws + oA + (4u<<20));               //  8 MB fp32 [B][N][256]
  unsigned short* x1b    = (unsigned short*)(ws + oA + (12u<<20));     //  4 MB bf16 [B][N][256]
  unsigned short* h_b    = (unsigned short*)(ws + oA + (16u<<20));     // 16 MB bf16 [B][N][1024]
  // region B: weights + casted x + qkv
  const size_t oB = oA + (32u<<20);
  unsigned short* Wqkv_b  = (unsigned short*)(ws + oB);                // 384 KB [768][256]
  unsigned short* Wproj_b = (unsigned short*)(ws + oB + 393216);       // 128 KB
  unsigned short* W1_b    = (unsigned short*)(ws + oB + 524288);       // 512 KB
  unsigned short* W2_b    = (unsigned short*)(ws + oB + 1048576);      // 512 KB
  unsigned short* xb      = (unsigned short*)(ws + oB + 1572864);      //   4 MB bf16 [B][N][256]
  float*          xf      = (float*)(ws + oB + 1572864 + (4u<<20));    //   8 MB fp32 [B][N][256]
  unsigned short* qkv     = (unsigned short*)(ws + oB + 1572864 + (12u<<20)); // 12 MB bf16 [B][N][768]

  stage1_kernel<<<4097, 256, 0, stream>>>(x, xb, xf, xyz, Pp,
                                          Wq, Wkv, Wproj, ffn_w1, ffn_w2,
                                          Wqkv_b, Wproj_b, W1_b, W2_b,
                                          rp_w1, rp_g, rp_b, rp_m, rp_v, rp_w2,
                                          w1f, W2t);

  MG pqkv = {xb, Wqkv_b, 256, 768, qkv, nullptr,
             nullptr, nullptr, nullptr, nullptr, nullptr, nullptr};
  stage2_kernel<<<2816, 256, 0, stream>>>(Pp, idx, pqkv);

  attn_kernel<<<(BB*NPT)/4, 256, 0, stream>>>(qkv, w1f, W2t, xyz, idx, attn_b);

  MG pproj = {attn_b, Wproj_b, 256, 256, x1b, x1f,
              nullptr, xf, bn1_g, bn1_b, bn1_m, bn1_v};
  mgemm_kernel<2, 1><<<dim3(64, 4, BB), 256, 0, stream>>>(pproj);

  MG pf1 = {x1b, W1_b, 256, 1024, h_b, nullptr,
            ffn_b1, nullptr, nullptr, nullptr, nullptr, nullptr};
  mgemm_kernel<1, 2><<<dim3(32, 16, BB), 256, 0, stream>>>(pf1);

  MG pf2 = {h_b, W2_b, 1024, 256, nullptr, (float*)d_out,
            ffn_b2, x1f, bn2_g, bn2_b, bn2_m, bn2_v};
  mgemm_kernel<3, 1><<<dim3(64, 4, BB), 256, 0, stream>>>(pf2);
}

// Round 2
// 230.100 us; speedup vs baseline: 1.0941x; 1.0596x over previous
//
#include <hip/hip_runtime.h>
#include <math.h>

#define BB   2
#define CC   256
#define NPT  4096
#define HH   4
#define DD   64
#define KNN  16
#define EPSBN 1e-5f

typedef __attribute__((ext_vector_type(8))) short short8;
typedef __attribute__((ext_vector_type(4))) float f32x4;

typedef __attribute__((address_space(3))) unsigned int lds_u32;
typedef const __attribute__((address_space(1))) unsigned int glb_u32;
__device__ __forceinline__ void gl_lds16(const void* g, void* l) {
  __builtin_amdgcn_global_load_lds((glb_u32*)g, (lds_u32*)l, 16, 0, 0);
}

__device__ __forceinline__ unsigned short f2b(float f) {
  union { float f; unsigned int u; } v; v.f = f;
  unsigned int r = (v.u + 0x7FFFu + ((v.u >> 16) & 1u)) >> 16;
  return (unsigned short)r;
}
__device__ __forceinline__ void up2(unsigned int u, float& a, float& b) {
  union { unsigned int x; float f; } lo, hi;
  lo.x = u << 16; hi.x = u & 0xffff0000u;
  a = lo.f; b = hi.f;
}
__device__ __forceinline__ void up16(uint4 u0, uint4 u1, float* f) {
  up2(u0.x, f[0], f[1]);  up2(u0.y, f[2], f[3]);
  up2(u0.z, f[4], f[5]);  up2(u0.w, f[6], f[7]);
  up2(u1.x, f[8], f[9]);  up2(u1.y, f[10], f[11]);
  up2(u1.z, f[12], f[13]); up2(u1.w, f[14], f[15]);
}

// v_med3_u32: 1-op sorted-list insert step (no builtin on gfx950 -> inline asm)
__device__ __forceinline__ unsigned int med3u(unsigned int a, unsigned int b, unsigned int c) {
  unsigned int d;
  asm("v_med3_u32 %0, %1, %2, %3" : "=v"(d) : "v"(a), "v"(b), "v"(c));
  return d;
}

// ================= stage 1 bodies (independent work, fused dispatch) =================
__device__ __forceinline__
void wcast_body(const float* Wq, const float* Wkv, const float* Wp,
                const float* W1, const float* W2,
                unsigned short* oQKV, unsigned short* oP,
                unsigned short* o1, unsigned short* o2,
                const float* rp_w1, const float* rp_g, const float* rp_b,
                const float* rp_m, const float* rp_v, const float* rp_w2,
                float4* w1f, float4* W2t, int blk) {
  if (blk == 3072) {            // prep: fold rp BN into w1, reduce rp_w2 over heads
    int c = threadIdx.x;
    float s  = rp_g[c] / sqrtf(rp_v[c] + EPSBN);
    float b0 = rp_b[c] - rp_m[c] * s;
    w1f[c] = make_float4(rp_w1[c*3+0]*s, rp_w1[c*3+1]*s, rp_w1[c*3+2]*s, b0);
    float a0=0.f,a1=0.f,a2=0.f,a3=0.f;
    for (int o = 0; o < 64; o++) {
      a0 += rp_w2[(      o)*CC + c];
      a1 += rp_w2[( 64 + o)*CC + c];
      a2 += rp_w2[(128 + o)*CC + c];
      a3 += rp_w2[(192 + o)*CC + c];
    }
    W2t[c] = make_float4(a0,a1,a2,a3);
    return;
  }
  int i = blk * 256 + threadIdx.x;          // 786432 total
  if (i < 65536)        oQKV[i] = f2b(Wq[i]);
  else if (i < 196608)  oQKV[i] = f2b(Wkv[i - 65536]);
  else if (i < 262144)  oP[i - 196608] = f2b(Wp[i - 196608]);
  else if (i < 524288)  o1[i - 262144] = f2b(W1[i - 262144]);
  else                  o2[i - 524288] = f2b(W2[i - 524288]);
}

__device__ __forceinline__
void xcast_body(const float* x, unsigned short* xb, float* xf,
                float (*T)[65], int bx, int by, int bz) {
  int n0 = bx * 64, c0 = by * 64, bb = bz;
  int tid = threadIdx.x;
  {
    int crow = tid >> 2, ns = (tid & 3) * 16;
    const float* xp = x + ((size_t)(bb*CC + c0 + crow))*NPT + n0 + ns;
#pragma unroll
    for (int i = 0; i < 4; i++) {
      float4 v = ((const float4*)xp)[i];
      T[crow][ns + i*4 + 0] = v.x; T[crow][ns + i*4 + 1] = v.y;
      T[crow][ns + i*4 + 2] = v.z; T[crow][ns + i*4 + 3] = v.w;
    }
  }
  __syncthreads();
  {
    int nrow = tid >> 2, cs = (tid & 3) * 16;
    float vals[16];
#pragma unroll
    for (int i = 0; i < 16; i++) vals[i] = T[cs + i][nrow];
    size_t orow = ((size_t)(bb*NPT + n0 + nrow))*CC + c0 + cs;
#pragma unroll
    for (int i = 0; i < 4; i++)
      *(float4*)&xf[orow + i*4] = make_float4(vals[i*4], vals[i*4+1], vals[i*4+2], vals[i*4+3]);
    unsigned short us[16];
#pragma unroll
    for (int i = 0; i < 16; i++) us[i] = f2b(vals[i]);
    *(uint4*)&xb[orow]     = *(const uint4*)&us[0];
    *(uint4*)&xb[orow + 8] = *(const uint4*)&us[8];
  }
}

// KNN stage 1: packed-u32 sorted-insert via v_med3_u32 — 1 op/position.
// Insertion into ascending list k0..k15 (applied DESCENDING so old k_{i-1} is read):
//   k_i' = med3(key, k_{i-1}, k_i);  k0' = min(key, k0)
// Keys are (non-negative float bits & ~0x1FF) | within-512-chunk index, so u32
// order == (distance, index) order and sentinels 0xFFFFFFFF sort last.
#define MPROC(M4, MI) { \
    float nd = fmaf(qx2, (M4).x, fmaf(qy2, (M4).y, fmaf(qz2, (M4).z, (M4).w + qsq))); \
    nd = fmaxf(nd, 0.f); \
    unsigned int key = (__float_as_uint(nd) & 0xFFFFFE00u) | (unsigned int)(MI); \
    k15 = med3u(key, k14, k15); k14 = med3u(key, k13, k14); \
    k13 = med3u(key, k12, k13); k12 = med3u(key, k11, k12); \
    k11 = med3u(key, k10, k11); k10 = med3u(key, k9,  k10); \
    k9  = med3u(key, k8,  k9 ); k8  = med3u(key, k7,  k8 ); \
    k7  = med3u(key, k6,  k7 ); k6  = med3u(key, k5,  k6 ); \
    k5  = med3u(key, k4,  k5 ); k4  = med3u(key, k3,  k4 ); \
    k3  = med3u(key, k2,  k3 ); k2  = med3u(key, k1,  k2 ); \
    k1  = med3u(key, k0,  k1 ); k0  = min(key, k0); }

// Block stages one 512-pt chunk (sp[512], 8 KB); wave wv takes 128 candidates
// (R0's 4-blocks/CU occupancy config). Lists stored as RAW u32 keys: the entry's
// position in the query's 512-entry array encodes the chunk (s = pos>>6 in lanes),
// so global idx is reconstructible -> Pp stays 16 MB despite 32 lists/query.
__device__ __forceinline__
void knn_partial_body(const float* xyz, unsigned int* Pp, float4* sp,
                      int s, int qg, int b) {
  const float* base = xyz + (size_t)b * 3 * NPT;
  int c0 = s * 512;
  for (int i = threadIdx.x; i < 512; i += 256) {
    float mx = base[c0 + i], my = base[NPT + c0 + i], mz = base[2*NPT + c0 + i];
    sp[i] = make_float4(mx, my, mz, mx*mx + my*my + mz*mz);
  }
  int lane = threadIdx.x & 63;
  int wv   = threadIdx.x >> 6;
  int qn   = qg * 64 + lane;
  float qx = base[qn], qy = base[NPT + qn], qz = base[2*NPT + qn];
  float qsq = qx*qx + qy*qy + qz*qz;
  float qx2 = -2.f*qx, qy2 = -2.f*qy, qz2 = -2.f*qz;
  __syncthreads();

  unsigned int k0=0xFFFFFFFFu,k1=0xFFFFFFFFu,k2=0xFFFFFFFFu,k3=0xFFFFFFFFu,
               k4=0xFFFFFFFFu,k5=0xFFFFFFFFu,k6=0xFFFFFFFFu,k7=0xFFFFFFFFu,
               k8=0xFFFFFFFFu,k9=0xFFFFFFFFu,k10=0xFFFFFFFFu,k11=0xFFFFFFFFu,
               k12=0xFFFFFFFFu,k13=0xFFFFFFFFu,k14=0xFFFFFFFFu,k15=0xFFFFFFFFu;

  int sb = wv * 128;            // wave's sub-chunk; payload = within-512 index
  for (int mm = 0; mm < 128; mm += 4) {
    float4 a = sp[sb+mm], bq = sp[sb+mm+1], cq = sp[sb+mm+2], dq = sp[sb+mm+3];
    MPROC(a,  sb+mm)
    MPROC(bq, sb+mm+1)
    MPROC(cq, sb+mm+2)
    MPROC(dq, sb+mm+3)
  }

  int gq = b * NPT + qn;
  uint4* out = (uint4*)(Pp + (size_t)gq * 512 + (size_t)(s*4 + wv) * 16);
  out[0] = make_uint4(k0,  k1,  k2,  k3);
  out[1] = make_uint4(k4,  k5,  k6,  k7);
  out[2] = make_uint4(k8,  k9,  k10, k11);
  out[3] = make_uint4(k12, k13, k14, k15);
}

// stage1 fused dispatch: [0,1024) knn | [1024,1536) xcast | [1536,4609) wcast.
// knn FIRST so the VALU-bound tail starts at t=0 and the memory-bound cast blocks
// co-schedule under it. LDS union: xcast 64x65 tile / knn sp[512] (16.6 KB pool).
__global__ __launch_bounds__(256) __attribute__((amdgpu_waves_per_eu(1, 4)))
void stage1_kernel(const float* x, unsigned short* xb, float* xf,
                   const float* xyz, unsigned int* Pp,
                   const float* Wq, const float* Wkv, const float* Wp,
                   const float* W1, const float* W2,
                   unsigned short* oQKV, unsigned short* oP,
                   unsigned short* o1, unsigned short* o2,
                   const float* rp_w1, const float* rp_g, const float* rp_b,
                   const float* rp_m, const float* rp_v, const float* rp_w2,
                   float4* w1f, float4* W2t) {
  __shared__ __align__(16) char smem[64*65*4];
  int bi = blockIdx.x;
  if (bi < 1024) {
    knn_partial_body(xyz, Pp, (float4*)smem, bi & 7, (bi >> 3) & 63, bi >> 9);
  } else if (bi < 1536) {
    int i = bi - 1024;
    xcast_body(x, xb, xf, (float(*)[65])smem, i & 63, (i >> 6) & 3, i >> 8);
  } else {
    wcast_body(Wq, Wkv, Wp, W1, W2, oQKV, oP, o1, o2,
               rp_w1, rp_g, rp_b, rp_m, rp_v, rp_w2, w1f, W2t, bi - 1536);
  }
}

// ================= stage 2: knn_merge + qkv GEMM (independent, fused) ================
// Entry e of a query's 512-entry array came from chunk s = e>>6 (list L = e>>4,
// s = L>>2). Lane reads 8 consecutive entries at e = lane*8 -> s = lane>>3.
__device__ __forceinline__
void knn_merge_body(const unsigned int* Pp, int* idx_out, int blk) {
  int wv   = threadIdx.x >> 6;
  int lane = threadIdx.x & 63;
  int gq   = blk * 4 + wv;
  float d[8]; int ii[8];
  const uint4* base = (const uint4*)(Pp + (size_t)gq * 512);
  int gbase = (lane >> 3) * 512;
  {
    uint4 v0 = base[lane*2], v1 = base[lane*2 + 1];
    unsigned int ks[8] = {v0.x, v0.y, v0.z, v0.w, v1.x, v1.y, v1.z, v1.w};
#pragma unroll
    for (int t = 0; t < 8; t++) {
      d[t]  = __uint_as_float(ks[t] & 0xFFFFFE00u);
      ii[t] = gbase + (int)(ks[t] & 0x1FFu);
    }
  }
  for (int sel = 0; sel < 16; sel++) {
    float bd = 3.5e38f; int bi = 0x7fffffff;
#pragma unroll
    for (int t = 0; t < 8; t++) {
      bool better = (d[t] < bd) || (d[t] == bd && ii[t] < bi);
      if (better) { bd = d[t]; bi = ii[t]; }
    }
#pragma unroll
    for (int off = 1; off < 64; off <<= 1) {
      float od = __shfl_xor(bd, off, 64);
      int   oi = __shfl_xor(bi, off, 64);
      if (od < bd || (od == bd && oi < bi)) { bd = od; bi = oi; }
    }
#pragma unroll
    for (int t = 0; t < 8; t++)
      if (ii[t] == bi) d[t] = 3.5e38f;
    if (lane == 0) idx_out[gq*16 + sel] = bi;
  }
}

// ------- MFMA bf16 GEMM v3: NT-templated N-tile (NT*64 rows) ------------------------
struct MG {
  const unsigned short* A; const unsigned short* Wt; int K; int M;
  unsigned short* OutB; float* OutF;
  const float* bias; const float* resid;
  const float* bng; const float* bnb; const float* bnm; const float* bnv;
};

template<int EPI, int NT>
__device__ __forceinline__ void mgemm_body(const MG& p, int bx, int by, int bz) {
  __shared__ unsigned short As[NT*64*64];
  __shared__ unsigned short Bs[64*64];
  const int tid  = threadIdx.x;
  const int bb   = bz;
  const int n0   = bx * (NT*64);
  const int m0   = by * 64;
  const int lane = tid & 63;
  const int wv   = tid >> 6;
  const int l15  = lane & 15;
  const int quad = lane >> 4;
  const int K    = p.K;
  const int WR   = NT*16;                   // wave row span

  f32x4 acc[NT][4];
#pragma unroll
  for (int i = 0; i < NT; i++)
#pragma unroll
    for (int j = 0; j < 4; j++) acc[i][j] = (f32x4){0.f, 0.f, 0.f, 0.f};

  const int srow = wv*8 + (lane >> 3);
  const int pseg = lane & 7;
  const unsigned short* Abase = p.A  + (size_t)bb*NPT*K;

  for (int c0 = 0; c0 < K; c0 += 64) {
#pragma unroll
    for (int t = 0; t < NT*2; t++) {
      int row = t*32 + srow;
      int ls  = pseg ^ (row & 7);
      gl_lds16(Abase + (size_t)(n0 + row)*K + c0 + ls*8,
               &As[wv*512 + t*2048 + lane*8]);
    }
#pragma unroll
    for (int t = 0; t < 2; t++) {
      int row = t*32 + srow;
      int ls  = pseg ^ (row & 7);
      gl_lds16(p.Wt + (size_t)(m0 + row)*K + c0 + ls*8,
               &Bs[wv*512 + t*2048 + lane*8]);
    }
    __syncthreads();
    short8 bf[4][2];
#pragma unroll
    for (int mt = 0; mt < 4; mt++)
#pragma unroll
      for (int kk = 0; kk < 2; kk++) {
        int row = mt*16 + l15;
        int ps  = (kk*4 + quad) ^ (row & 7);
        bf[mt][kk] = *(const short8*)&Bs[row*64 + ps*8];
      }
#pragma unroll
    for (int nt = 0; nt < NT; nt++)
#pragma unroll
      for (int kk = 0; kk < 2; kk++) {
        int row = wv*WR + nt*16 + l15;
        int ps  = (kk*4 + quad) ^ (row & 7);
        short8 af = *(const short8*)&As[row*64 + ps*8];
#pragma unroll
        for (int mt = 0; mt < 4; mt++)
          acc[nt][mt] = __builtin_amdgcn_mfma_f32_16x16x32_bf16(af, bf[mt][kk], acc[nt][mt], 0, 0, 0);
      }
    __syncthreads();
  }

  if (EPI == 0 || EPI == 1) {
    float bs[4];
#pragma unroll
    for (int mt = 0; mt < 4; mt++)
      bs[mt] = (EPI == 1) ? p.bias[m0 + mt*16 + l15] : 0.f;
#pragma unroll
    for (int nt = 0; nt < NT; nt++)
#pragma unroll
      for (int reg = 0; reg < 4; reg++) {
        size_t row = ((size_t)(bb*NPT + n0 + wv*WR + nt*16 + quad*4 + reg))*p.M + m0;
#pragma unroll
        for (int mt = 0; mt < 4; mt++) {
          float v = acc[nt][mt][reg] + bs[mt];
          if (EPI == 1) v = fmaxf(v, 0.f);
          p.OutB[row + mt*16 + l15] = f2b(v);
        }
      }
  } else if (EPI == 2) {
    float sc[4], sh[4];
#pragma unroll
    for (int mt = 0; mt < 4; mt++) {
      int m = m0 + mt*16 + l15;
      float s = p.bng[m] / sqrtf(p.bnv[m] + EPSBN);
      sc[mt] = s; sh[mt] = p.bnb[m] - p.bnm[m]*s;
    }
#pragma unroll
    for (int nt = 0; nt < NT; nt++)
#pragma unroll
      for (int reg = 0; reg < 4; reg++) {
        size_t row = ((size_t)(bb*NPT + n0 + wv*WR + nt*16 + quad*4 + reg))*p.M + m0;
#pragma unroll
        for (int mt = 0; mt < 4; mt++) {
          float r = p.resid[row + mt*16 + l15];
          float v = (acc[nt][mt][reg] + r)*sc[mt] + sh[mt];
          p.OutF[row + mt*16 + l15] = v;
          p.OutB[row + mt*16 + l15] = f2b(v);
        }
      }
  } else {  // EPI == 3
    __shared__ float Tb[4][4][16*17];
    float sc[4], sh[4], bs[4];
#pragma unroll
    for (int mt = 0; mt < 4; mt++) {
      int m = m0 + mt*16 + l15;
      float s = p.bng[m] / sqrtf(p.bnv[m] + EPSBN);
      sc[mt] = s; sh[mt] = p.bnb[m] - p.bnm[m]*s;
      bs[mt] = p.bias[m];
    }
#pragma unroll
    for (int nt = 0; nt < NT; nt++) {
#pragma unroll
      for (int reg = 0; reg < 4; reg++) {
        size_t row = ((size_t)(bb*NPT + n0 + wv*WR + nt*16 + quad*4 + reg))*p.M + m0;
#pragma unroll
        for (int mt = 0; mt < 4; mt++) {
          float r = p.resid[row + mt*16 + l15];
          float v = (acc[nt][mt][reg] + bs[mt] + r)*sc[mt] + sh[mt];
          Tb[wv][mt][(quad*4 + reg)*17 + l15] = v;
        }
      }
      __syncthreads();
#pragma unroll
      for (int mt = 0; mt < 4; mt++)
#pragma unroll
        for (int reg = 0; reg < 4; reg++) {
          float v = Tb[wv][mt][l15*17 + quad*4 + reg];
          p.OutF[((size_t)(bb*p.M + m0 + mt*16 + quad*4 + reg))*NPT
                 + n0 + wv*WR + nt*16 + l15] = v;
        }
      __syncthreads();
    }
  }
}

template<int EPI, int NT>
__global__ __launch_bounds__(256)
void mgemm_kernel(MG p) { mgemm_body<EPI, NT>(p, blockIdx.x, blockIdx.y, blockIdx.z); }

// stage2 fused: [0,2048) knn_merge | [2048,2816) qkv GEMM (grid 32x12x2 linearized)
__global__ __launch_bounds__(256)
void stage2_kernel(const unsigned int* Pp, int* idx, MG pqkv) {
  int bi = blockIdx.x;
  if (bi < 2048) {
    knn_merge_body(Pp, idx, bi);
  } else {
    int i = bi - 2048;
    mgemm_body<0, 2>(pqkv, i & 31, (i >> 5) % 12, i / 384);
  }
}

// ---------------- fused attention v4: 4 points/block, shared weight reads ----------
__global__ __launch_bounds__(256, 4)
void attn_kernel(const unsigned short* __restrict__ qkv, const float4* __restrict__ w1f,
                 const float4* __restrict__ W2t, const float* __restrict__ xyz,
                 const int* __restrict__ idx, unsigned short* __restrict__ attn_b) {
  __shared__ float4 sw1[256];
  __shared__ float4 sw2[256];
  __shared__ int   sidx[4][16];
  __shared__ float srel[4][16][4];
  __shared__ float sbias[4][16][4];
  __shared__ float red[4][16*68];
  int tid = threadIdx.x;
  int bn0 = blockIdx.x * 4;
  int b   = bn0 >> 12;
  sw1[tid] = w1f[tid];
  sw2[tid] = W2t[tid];
  if (tid < 64) {
    int p = tid >> 4, kk = tid & 15;
    int bn = bn0 + p, n = bn & 4095;
    int j = idx[bn*16 + kk];
    sidx[p][kk] = j;
    const float* pb = xyz + (size_t)b * 3 * NPT;
    srel[p][kk][0] = pb[j]         - pb[n];
    srel[p][kk][1] = pb[NPT + j]   - pb[NPT + n];
    srel[p][kk][2] = pb[2*NPT + j] - pb[2*NPT + n];
  }
  __syncthreads();
  {  // ---- bias phase: 4 points per weight read ----
    int kk = tid >> 4, cs = tid & 15;
    float rx[4], ry[4], rz[4], h[4][4];
#pragma unroll
    for (int p = 0; p < 4; p++) {
      rx[p] = srel[p][kk][0]; ry[p] = srel[p][kk][1]; rz[p] = srel[p][kk][2];
#pragma unroll
      for (int q = 0; q < 4; q++) h[p][q] = 0.f;
    }
#pragma unroll
    for (int i = 0; i < 16; i++) {
      int c = cs*16 + ((i + cs) & 15);
      float4 w  = sw1[c];
      float4 w2 = sw2[c];
#pragma unroll
      for (int p = 0; p < 4; p++) {
        float t0 = fmaxf(fmaf(rx[p], w.x, fmaf(ry[p], w.y, fmaf(rz[p], w.z, w.w))), 0.f);
        h[p][0] = fmaf(t0, w2.x, h[p][0]); h[p][1] = fmaf(t0, w2.y, h[p][1]);
        h[p][2] = fmaf(t0, w2.z, h[p][2]); h[p][3] = fmaf(t0, w2.w, h[p][3]);
      }
    }
#pragma unroll
    for (int off = 1; off < 16; off <<= 1)
#pragma unroll
      for (int p = 0; p < 4; p++)
#pragma unroll
        for (int q = 0; q < 4; q++)
          h[p][q] += __shfl_xor(h[p][q], off, 64);
    if (cs == 0)
#pragma unroll
      for (int p = 0; p < 4; p++)
#pragma unroll
        for (int q = 0; q < 4; q++) sbias[p][kk][q] = h[p][q];
  }
  __syncthreads();
  // ---- attention phase: 4 points serial ----
  int wv   = tid >> 6;
  int lane = tid & 63;
  int k    = lane >> 2;
  int c4   = lane & 3;
  int ch0  = wv*64 + c4*16;
  size_t base = (size_t)(b*NPT) * 768;
#pragma unroll 1
  for (int p = 0; p < 4; p++) {
    int bn = bn0 + p;
    size_t rowq = (size_t)bn * 768;
    float qf[16];
    {
      uint4 q0 = *(const uint4*)(qkv + rowq + ch0);
      uint4 q1 = *(const uint4*)(qkv + rowq + ch0 + 8);
      up16(q0, q1, qf);
    }
    int j = sidx[p][k];
    float dot = 0.f;
    {
      const unsigned short* krow = qkv + base + (size_t)j*768 + 256 + ch0;
      uint4 k0 = *(const uint4*)(krow);
      uint4 k1 = *(const uint4*)(krow + 8);
      float kf[16];
      up16(k0, k1, kf);
#pragma unroll
      for (int i = 0; i < 16; i++) dot = fmaf(qf[i], kf[i], dot);
    }
    dot += __shfl_xor(dot, 1, 64);
    dot += __shfl_xor(dot, 2, 64);
    float logit = dot * 0.125f + sbias[p][k][wv];
    float mx = logit;
#pragma unroll
    for (int off = 4; off < 64; off <<= 1) mx = fmaxf(mx, __shfl_xor(mx, off, 64));
    float e = __expf(logit - mx);
    float ssum = e;
#pragma unroll
    for (int off = 4; off < 64; off <<= 1) ssum += __shfl_xor(ssum, off, 64);
    float w = e / ssum;
    {
      const unsigned short* vrow = qkv + base + (size_t)j*768 + 512 + ch0;
      uint4 v0 = *(const uint4*)(vrow);
      uint4 v1 = *(const uint4*)(vrow + 8);
      float vf[16];
      up16(v0, v1, vf);
      float* dst = &red[wv][k*68 + c4*16];
#pragma unroll
      for (int g = 0; g < 4; g++)
        ((float4*)dst)[g] = make_float4(w*vf[g*4], w*vf[g*4+1], w*vf[g*4+2], w*vf[g*4+3]);
    }
    __syncthreads();
    float o = 0.f;
#pragma unroll
    for (int kk2 = 0; kk2 < 16; kk2++) o += red[wv][kk2*68 + lane];
    attn_b[(size_t)bn*256 + wv*64 + lane] = f2b(o);
    __syncthreads();
  }
}

extern "C" void kernel_launch(void* const* d_in, const int* in_sizes, int n_in,
                              void* d_out, int out_size, void* d_ws, size_t ws_size,
                              hipStream_t stream) {
  const float* x     = (const float*)d_in[0];
  const float* xyz   = (const float*)d_in[1];
  const float* Wq    = (const float*)d_in[2];
  const float* Wkv   = (const float*)d_in[3];
  const float* Wproj = (const float*)d_in[4];
  const float* rp_w1 = (const float*)d_in[5];
  const float* rp_g  = (const float*)d_in[6];
  const float* rp_b  = (const float*)d_in[7];
  const float* rp_m  = (const float*)d_in[8];
  const float* rp_v  = (const float*)d_in[9];
  const float* rp_w2 = (const float*)d_in[10];
  const float* bn1_g = (const float*)d_in[11];
  const float* bn1_b = (const float*)d_in[12];
  const float* bn1_m = (const float*)d_in[13];
  const float* bn1_v = (const float*)d_in[14];
  const float* bn2_g = (const float*)d_in[15];
  const float* bn2_b = (const float*)d_in[16];
  const float* bn2_m = (const float*)d_in[17];
  const float* bn2_v = (const float*)d_in[18];
  const float* ffn_w1 = (const float*)d_in[19];
  const float* ffn_b1 = (const float*)d_in[20];
  const float* ffn_w2 = (const float*)d_in[21];
  const float* ffn_b2 = (const float*)d_in[22];

  char* ws = (char*)d_ws;
  // static region
  float4* w1f = (float4*)(ws + 0);                         //   4 KB
  float4* W2t = (float4*)(ws + 4096);                      //   4 KB
  int*    idx = (int*)  (ws + 8192);                       // 512 KB
  // reuse region A (32 MB): KNN scratch first, then post-attn tensors
  const size_t oA = 532480;
  unsigned int*   Pp     = (unsigned int*)(ws + oA);       // 16 MB u32 [B*N][512] keys
  unsigned short* attn_b = (unsigned short*)(ws + oA);                 //  4 MB bf16 [B][N][256]
  float*          x1f    = (float*)(ws + oA + (4u<<20));               //  8 MB fp32 [B][N][256]
  unsigned short* x1b    = (unsigned short*)(ws + oA + (12u<<20));     //  4 MB bf16 [B][N][256]
  unsigned short* h_b    = (unsigned short*)(ws + oA + (16u<<20));     // 16 MB bf16 [B][N][1024]
  // region B: weights + casted x + qkv
  const size_t oB = oA + (32u<<20);
  unsigned short* Wqkv_b  = (unsigned short*)(ws + oB);                // 384 KB [768][256]
  unsigned short* Wproj_b = (unsigned short*)(ws + oB + 393216);       // 128 KB
  unsigned short* W1_b    = (unsigned short*)(ws + oB + 524288);       // 512 KB
  unsigned short* W2_b    = (unsigned short*)(ws + oB + 1048576);      // 512 KB
  unsigned short* xb      = (unsigned short*)(ws + oB + 1572864);      //   4 MB bf16 [B][N][256]
  float*          xf      = (float*)(ws + oB + 1572864 + (4u<<20));    //   8 MB fp32 [B][N][256]
  unsigned short* qkv     = (unsigned short*)(ws + oB + 1572864 + (12u<<20)); // 12 MB bf16 [B][N][768]

  stage1_kernel<<<4609, 256, 0, stream>>>(x, xb, xf, xyz, Pp,
                                          Wq, Wkv, Wproj, ffn_w1, ffn_w2,
                                          Wqkv_b, Wproj_b, W1_b, W2_b,
                                          rp_w1, rp_g, rp_b, rp_m, rp_v, rp_w2,
                                          w1f, W2t);

  MG pqkv = {xb, Wqkv_b, 256, 768, qkv, nullptr,
             nullptr, nullptr, nullptr, nullptr, nullptr, nullptr};
  stage2_kernel<<<2816, 256, 0, stream>>>(Pp, idx, pqkv);

  attn_kernel<<<(BB*NPT)/4, 256, 0, stream>>>(qkv, w1f, W2t, xyz, idx, attn_b);

  MG pproj = {attn_b, Wproj_b, 256, 256, x1b, x1f,
              nullptr, xf, bn1_g, bn1_b, bn1_m, bn1_v};
  mgemm_kernel<2, 1><<<dim3(64, 4, BB), 256, 0, stream>>>(pproj);

  MG pf1 = {x1b, W1_b, 256, 1024, h_b, nullptr,
            ffn_b1, nullptr, nullptr, nullptr, nullptr, nullptr};
  mgemm_kernel<1, 2><<<dim3(32, 16, BB), 256, 0, stream>>>(pf1);

  MG pf2 = {h_b, W2_b, 1024, 256, nullptr, (float*)d_out,
            ffn_b2, x1f, bn2_g, bn2_b, bn2_m, bn2_v};
  mgemm_kernel<3, 1><<<dim3(64, 4, BB), 256, 0, stream>>>(pf2);
}

// Round 3
// 222.071 us; speedup vs baseline: 1.1336x; 1.0362x over previous
//
#include <hip/hip_runtime.h>
#include <math.h>

#define BB   2
#define CC   256
#define NPT  4096
#define HH   4
#define DD   64
#define KNN  16
#define EPSBN 1e-5f

typedef __attribute__((ext_vector_type(8))) short short8;
typedef __attribute__((ext_vector_type(4))) float f32x4;

typedef __attribute__((address_space(3))) unsigned int lds_u32;
typedef const __attribute__((address_space(1))) unsigned int glb_u32;
__device__ __forceinline__ void gl_lds16(const void* g, void* l) {
  __builtin_amdgcn_global_load_lds((glb_u32*)g, (lds_u32*)l, 16, 0, 0);
}

__device__ __forceinline__ unsigned short f2b(float f) {
  union { float f; unsigned int u; } v; v.f = f;
  unsigned int r = (v.u + 0x7FFFu + ((v.u >> 16) & 1u)) >> 16;
  return (unsigned short)r;
}
__device__ __forceinline__ void up2(unsigned int u, float& a, float& b) {
  union { unsigned int x; float f; } lo, hi;
  lo.x = u << 16; hi.x = u & 0xffff0000u;
  a = lo.f; b = hi.f;
}
__device__ __forceinline__ void up16(uint4 u0, uint4 u1, float* f) {
  up2(u0.x, f[0], f[1]);  up2(u0.y, f[2], f[3]);
  up2(u0.z, f[4], f[5]);  up2(u0.w, f[6], f[7]);
  up2(u1.x, f[8], f[9]);  up2(u1.y, f[10], f[11]);
  up2(u1.z, f[12], f[13]); up2(u1.w, f[14], f[15]);
}

// v_med3_u32: 1-op sorted-list insert step (no builtin on gfx950 -> inline asm)
__device__ __forceinline__ unsigned int med3u(unsigned int a, unsigned int b, unsigned int c) {
  unsigned int d;
  asm("v_med3_u32 %0, %1, %2, %3" : "=v"(d) : "v"(a), "v"(b), "v"(c));
  return d;
}

// ================= stage 1 bodies (independent work, fused dispatch) =================
__device__ __forceinline__
void wcast_body(const float* Wq, const float* Wkv, const float* Wp,
                const float* W1, const float* W2,
                unsigned short* oQKV, unsigned short* oP,
                unsigned short* o1, unsigned short* o2,
                const float* rp_w1, const float* rp_g, const float* rp_b,
                const float* rp_m, const float* rp_v, const float* rp_w2,
                float4* w1f, float4* W2t, int blk) {
  if (blk == 3072) {            // prep: fold rp BN into w1, reduce rp_w2 over heads
    int c = threadIdx.x;
    float s  = rp_g[c] / sqrtf(rp_v[c] + EPSBN);
    float b0 = rp_b[c] - rp_m[c] * s;
    w1f[c] = make_float4(rp_w1[c*3+0]*s, rp_w1[c*3+1]*s, rp_w1[c*3+2]*s, b0);
    float a0=0.f,a1=0.f,a2=0.f,a3=0.f;
    for (int o = 0; o < 64; o++) {
      a0 += rp_w2[(      o)*CC + c];
      a1 += rp_w2[( 64 + o)*CC + c];
      a2 += rp_w2[(128 + o)*CC + c];
      a3 += rp_w2[(192 + o)*CC + c];
    }
    W2t[c] = make_float4(a0,a1,a2,a3);
    return;
  }
  int i = blk * 256 + threadIdx.x;          // 786432 total
  if (i < 65536)        oQKV[i] = f2b(Wq[i]);
  else if (i < 196608)  oQKV[i] = f2b(Wkv[i - 65536]);
  else if (i < 262144)  oP[i - 196608] = f2b(Wp[i - 196608]);
  else if (i < 524288)  o1[i - 262144] = f2b(W1[i - 262144]);
  else                  o2[i - 524288] = f2b(W2[i - 524288]);
}

__device__ __forceinline__
void xcast_body(const float* x, unsigned short* xb, float* xf,
                float (*T)[65], int bx, int by, int bz) {
  int n0 = bx * 64, c0 = by * 64, bb = bz;
  int tid = threadIdx.x;
  {
    int crow = tid >> 2, ns = (tid & 3) * 16;
    const float* xp = x + ((size_t)(bb*CC + c0 + crow))*NPT + n0 + ns;
#pragma unroll
    for (int i = 0; i < 4; i++) {
      float4 v = ((const float4*)xp)[i];
      T[crow][ns + i*4 + 0] = v.x; T[crow][ns + i*4 + 1] = v.y;
      T[crow][ns + i*4 + 2] = v.z; T[crow][ns + i*4 + 3] = v.w;
    }
  }
  __syncthreads();
  {
    int nrow = tid >> 2, cs = (tid & 3) * 16;
    float vals[16];
#pragma unroll
    for (int i = 0; i < 16; i++) vals[i] = T[cs + i][nrow];
    size_t orow = ((size_t)(bb*NPT + n0 + nrow))*CC + c0 + cs;
#pragma unroll
    for (int i = 0; i < 4; i++)
      *(float4*)&xf[orow + i*4] = make_float4(vals[i*4], vals[i*4+1], vals[i*4+2], vals[i*4+3]);
    unsigned short us[16];
#pragma unroll
    for (int i = 0; i < 16; i++) us[i] = f2b(vals[i]);
    *(uint4*)&xb[orow]     = *(const uint4*)&us[0];
    *(uint4*)&xb[orow + 8] = *(const uint4*)&us[8];
  }
}

// KNN stage 1: packed-u32 sorted-insert via v_med3_u32 — 1 op/position.
// Insertion into ascending list k0..k15 (applied DESCENDING so old k_{i-1} is read):
//   k_i' = med3(key, k_{i-1}, k_i);  k0' = min(key, k0)
// Keys are (non-negative float bits & ~0x1FF) | within-512-chunk index, so u32
// order == (distance, index) order and sentinels 0xFFFFFFFF sort last.
#define MPROC(M4, MI) { \
    float nd = fmaf(qx2, (M4).x, fmaf(qy2, (M4).y, fmaf(qz2, (M4).z, (M4).w + qsq))); \
    nd = fmaxf(nd, 0.f); \
    unsigned int key = (__float_as_uint(nd) & 0xFFFFFE00u) | (unsigned int)(MI); \
    k15 = med3u(key, k14, k15); k14 = med3u(key, k13, k14); \
    k13 = med3u(key, k12, k13); k12 = med3u(key, k11, k12); \
    k11 = med3u(key, k10, k11); k10 = med3u(key, k9,  k10); \
    k9  = med3u(key, k8,  k9 ); k8  = med3u(key, k7,  k8 ); \
    k7  = med3u(key, k6,  k7 ); k6  = med3u(key, k5,  k6 ); \
    k5  = med3u(key, k4,  k5 ); k4  = med3u(key, k3,  k4 ); \
    k3  = med3u(key, k2,  k3 ); k2  = med3u(key, k1,  k2 ); \
    k1  = med3u(key, k0,  k1 ); k0  = min(key, k0); }

// Block stages one 512-pt chunk (sp[512], 8 KB); wave wv takes 128 candidates.
// Lists stored as RAW u32 keys: entry position encodes the chunk (s = lane>>3 in
// the merge), so global idx is reconstructible -> Pp is 16 MB with 32 lists/query.
__device__ __forceinline__
void knn_partial_body(const float* xyz, unsigned int* Pp, float4* sp,
                      int s, int qg, int b) {
  const float* base = xyz + (size_t)b * 3 * NPT;
  int c0 = s * 512;
  for (int i = threadIdx.x; i < 512; i += 256) {
    float mx = base[c0 + i], my = base[NPT + c0 + i], mz = base[2*NPT + c0 + i];
    sp[i] = make_float4(mx, my, mz, mx*mx + my*my + mz*mz);
  }
  int lane = threadIdx.x & 63;
  int wv   = threadIdx.x >> 6;
  int qn   = qg * 64 + lane;
  float qx = base[qn], qy = base[NPT + qn], qz = base[2*NPT + qn];
  float qsq = qx*qx + qy*qy + qz*qz;
  float qx2 = -2.f*qx, qy2 = -2.f*qy, qz2 = -2.f*qz;
  __syncthreads();

  unsigned int k0=0xFFFFFFFFu,k1=0xFFFFFFFFu,k2=0xFFFFFFFFu,k3=0xFFFFFFFFu,
               k4=0xFFFFFFFFu,k5=0xFFFFFFFFu,k6=0xFFFFFFFFu,k7=0xFFFFFFFFu,
               k8=0xFFFFFFFFu,k9=0xFFFFFFFFu,k10=0xFFFFFFFFu,k11=0xFFFFFFFFu,
               k12=0xFFFFFFFFu,k13=0xFFFFFFFFu,k14=0xFFFFFFFFu,k15=0xFFFFFFFFu;

  int sb = wv * 128;            // wave's sub-chunk; payload = within-512 index
  for (int mm = 0; mm < 128; mm += 4) {
    float4 a = sp[sb+mm], bq = sp[sb+mm+1], cq = sp[sb+mm+2], dq = sp[sb+mm+3];
    MPROC(a,  sb+mm)
    MPROC(bq, sb+mm+1)
    MPROC(cq, sb+mm+2)
    MPROC(dq, sb+mm+3)
  }

  int gq = b * NPT + qn;
  uint4* out = (uint4*)(Pp + (size_t)gq * 512 + (size_t)(s*4 + wv) * 16);
  out[0] = make_uint4(k0,  k1,  k2,  k3);
  out[1] = make_uint4(k4,  k5,  k6,  k7);
  out[2] = make_uint4(k8,  k9,  k10, k11);
  out[3] = make_uint4(k12, k13, k14, k15);
}

// stage1 fused dispatch: [0,1024) knn | [1024,1536) xcast | [1536,4609) wcast.
// knn FIRST so the VALU-bound tail starts at t=0 and the memory-bound cast blocks
// co-schedule under it. LDS union: xcast 64x65 tile / knn sp[512] (16.6 KB pool).
__global__ __launch_bounds__(256) __attribute__((amdgpu_waves_per_eu(1, 4)))
void stage1_kernel(const float* x, unsigned short* xb, float* xf,
                   const float* xyz, unsigned int* Pp,
                   const float* Wq, const float* Wkv, const float* Wp,
                   const float* W1, const float* W2,
                   unsigned short* oQKV, unsigned short* oP,
                   unsigned short* o1, unsigned short* o2,
                   const float* rp_w1, const float* rp_g, const float* rp_b,
                   const float* rp_m, const float* rp_v, const float* rp_w2,
                   float4* w1f, float4* W2t) {
  __shared__ __align__(16) char smem[64*65*4];
  int bi = blockIdx.x;
  if (bi < 1024) {
    knn_partial_body(xyz, Pp, (float4*)smem, bi & 7, (bi >> 3) & 63, bi >> 9);
  } else if (bi < 1536) {
    int i = bi - 1024;
    xcast_body(x, xb, xf, (float(*)[65])smem, i & 63, (i >> 6) & 3, i >> 8);
  } else {
    wcast_body(Wq, Wkv, Wp, W1, W2, oQKV, oP, o1, o2,
               rp_w1, rp_g, rp_b, rp_m, rp_v, rp_w2, w1f, W2t, bi - 1536);
  }
}

// ================= stage 2: knn_merge + qkv GEMM (independent, fused) ================
// Merge v2: butterfly of "keep lowest-16 of two sorted 16-lists" instead of 16
// serial argmin extractions (the final output is permutation-invariant -> we only
// need the SET). Lane's 8 loaded entries are already sorted ascending (half of a
// stage-1 insertion-network list). Keys lifted to u64 = (maskedDist<<32)|globalIdx
// so a single u64 compare reproduces the exact (d, idx) tie-break order.
// 6 rounds: shuffle partner's reversed list, elementwise min64 (bitonic half-
// cleaner), then 4-stage bitonic re-sort — skipped on the last round (set only).
__device__ __forceinline__ unsigned long long min64(unsigned long long a, unsigned long long b) {
  return a < b ? a : b;
}
__device__ __forceinline__ void ce64(unsigned long long& x, unsigned long long& y) {
  unsigned long long a = x, b = y;
  bool lt = a < b;
  x = lt ? a : b;
  y = lt ? b : a;
}
__device__ __forceinline__
void knn_merge_body(const unsigned int* Pp, int* idx_out, int blk) {
  int wv   = threadIdx.x >> 6;
  int lane = threadIdx.x & 63;
  int gq   = blk * 4 + wv;
  const uint4* base = (const uint4*)(Pp + (size_t)gq * 512);
  uint4 v0 = base[lane*2], v1 = base[lane*2 + 1];
  unsigned int gb = (unsigned int)(lane >> 3) * 512u;   // chunk base of entry e=lane*8
  unsigned long long a[16];
  {
    unsigned int ks[8] = {v0.x, v0.y, v0.z, v0.w, v1.x, v1.y, v1.z, v1.w};
#pragma unroll
    for (int t = 0; t < 8; t++)
      a[t] = ((unsigned long long)(ks[t] & 0xFFFFFE00u) << 32) | (gb + (ks[t] & 0x1FFu));
#pragma unroll
    for (int t = 8; t < 16; t++) a[t] = ~0ull;
  }
#pragma unroll
  for (int r = 0; r < 6; r++) {
    const int m = 1 << r;
    unsigned long long t[16];
#pragma unroll
    for (int i = 0; i < 16; i++) {
      unsigned long long pb = __shfl_xor(a[15 - i], m, 64);
      t[i] = min64(a[i], pb);
    }
    if (r < 5) {
#pragma unroll
      for (int d = 8; d >= 1; d >>= 1)
#pragma unroll
        for (int i = 0; i < 16; i++)
          if ((i & d) == 0) ce64(t[i], t[i + d]);
    }
#pragma unroll
    for (int i = 0; i < 16; i++) a[i] = t[i];
  }
  if (lane == 0) {
    int4* o = (int4*)(idx_out + gq*16);
    o[0] = make_int4((int)(unsigned)a[0],  (int)(unsigned)a[1],
                     (int)(unsigned)a[2],  (int)(unsigned)a[3]);
    o[1] = make_int4((int)(unsigned)a[4],  (int)(unsigned)a[5],
                     (int)(unsigned)a[6],  (int)(unsigned)a[7]);
    o[2] = make_int4((int)(unsigned)a[8],  (int)(unsigned)a[9],
                     (int)(unsigned)a[10], (int)(unsigned)a[11]);
    o[3] = make_int4((int)(unsigned)a[12], (int)(unsigned)a[13],
                     (int)(unsigned)a[14], (int)(unsigned)a[15]);
  }
}

// ------- MFMA bf16 GEMM v3: NT-templated N-tile (NT*64 rows) ------------------------
struct MG {
  const unsigned short* A; const unsigned short* Wt; int K; int M;
  unsigned short* OutB; float* OutF;
  const float* bias; const float* resid;
  const float* bng; const float* bnb; const float* bnm; const float* bnv;
};

template<int EPI, int NT>
__device__ __forceinline__ void mgemm_body(const MG& p, int bx, int by, int bz) {
  __shared__ unsigned short As[NT*64*64];
  __shared__ unsigned short Bs[64*64];
  const int tid  = threadIdx.x;
  const int bb   = bz;
  const int n0   = bx * (NT*64);
  const int m0   = by * 64;
  const int lane = tid & 63;
  const int wv   = tid >> 6;
  const int l15  = lane & 15;
  const int quad = lane >> 4;
  const int K    = p.K;
  const int WR   = NT*16;                   // wave row span

  f32x4 acc[NT][4];
#pragma unroll
  for (int i = 0; i < NT; i++)
#pragma unroll
    for (int j = 0; j < 4; j++) acc[i][j] = (f32x4){0.f, 0.f, 0.f, 0.f};

  const int srow = wv*8 + (lane >> 3);
  const int pseg = lane & 7;
  const unsigned short* Abase = p.A  + (size_t)bb*NPT*K;

  for (int c0 = 0; c0 < K; c0 += 64) {
#pragma unroll
    for (int t = 0; t < NT*2; t++) {
      int row = t*32 + srow;
      int ls  = pseg ^ (row & 7);
      gl_lds16(Abase + (size_t)(n0 + row)*K + c0 + ls*8,
               &As[wv*512 + t*2048 + lane*8]);
    }
#pragma unroll
    for (int t = 0; t < 2; t++) {
      int row = t*32 + srow;
      int ls  = pseg ^ (row & 7);
      gl_lds16(p.Wt + (size_t)(m0 + row)*K + c0 + ls*8,
               &Bs[wv*512 + t*2048 + lane*8]);
    }
    __syncthreads();
    short8 bf[4][2];
#pragma unroll
    for (int mt = 0; mt < 4; mt++)
#pragma unroll
      for (int kk = 0; kk < 2; kk++) {
        int row = mt*16 + l15;
        int ps  = (kk*4 + quad) ^ (row & 7);
        bf[mt][kk] = *(const short8*)&Bs[row*64 + ps*8];
      }
#pragma unroll
    for (int nt = 0; nt < NT; nt++)
#pragma unroll
      for (int kk = 0; kk < 2; kk++) {
        int row = wv*WR + nt*16 + l15;
        int ps  = (kk*4 + quad) ^ (row & 7);
        short8 af = *(const short8*)&As[row*64 + ps*8];
#pragma unroll
        for (int mt = 0; mt < 4; mt++)
          acc[nt][mt] = __builtin_amdgcn_mfma_f32_16x16x32_bf16(af, bf[mt][kk], acc[nt][mt], 0, 0, 0);
      }
    __syncthreads();
  }

  if (EPI == 0 || EPI == 1) {
    float bs[4];
#pragma unroll
    for (int mt = 0; mt < 4; mt++)
      bs[mt] = (EPI == 1) ? p.bias[m0 + mt*16 + l15] : 0.f;
#pragma unroll
    for (int nt = 0; nt < NT; nt++)
#pragma unroll
      for (int reg = 0; reg < 4; reg++) {
        size_t row = ((size_t)(bb*NPT + n0 + wv*WR + nt*16 + quad*4 + reg))*p.M + m0;
#pragma unroll
        for (int mt = 0; mt < 4; mt++) {
          float v = acc[nt][mt][reg] + bs[mt];
          if (EPI == 1) v = fmaxf(v, 0.f);
          p.OutB[row + mt*16 + l15] = f2b(v);
        }
      }
  } else if (EPI == 2) {
    float sc[4], sh[4];
#pragma unroll
    for (int mt = 0; mt < 4; mt++) {
      int m = m0 + mt*16 + l15;
      float s = p.bng[m] / sqrtf(p.bnv[m] + EPSBN);
      sc[mt] = s; sh[mt] = p.bnb[m] - p.bnm[m]*s;
    }
#pragma unroll
    for (int nt = 0; nt < NT; nt++)
#pragma unroll
      for (int reg = 0; reg < 4; reg++) {
        size_t row = ((size_t)(bb*NPT + n0 + wv*WR + nt*16 + quad*4 + reg))*p.M + m0;
#pragma unroll
        for (int mt = 0; mt < 4; mt++) {
          float r = p.resid[row + mt*16 + l15];
          float v = (acc[nt][mt][reg] + r)*sc[mt] + sh[mt];
          p.OutF[row + mt*16 + l15] = v;
          p.OutB[row + mt*16 + l15] = f2b(v);
        }
      }
  } else {  // EPI == 3
    __shared__ float Tb[4][4][16*17];
    float sc[4], sh[4], bs[4];
#pragma unroll
    for (int mt = 0; mt < 4; mt++) {
      int m = m0 + mt*16 + l15;
      float s = p.bng[m] / sqrtf(p.bnv[m] + EPSBN);
      sc[mt] = s; sh[mt] = p.bnb[m] - p.bnm[m]*s;
      bs[mt] = p.bias[m];
    }
#pragma unroll
    for (int nt = 0; nt < NT; nt++) {
#pragma unroll
      for (int reg = 0; reg < 4; reg++) {
        size_t row = ((size_t)(bb*NPT + n0 + wv*WR + nt*16 + quad*4 + reg))*p.M + m0;
#pragma unroll
        for (int mt = 0; mt < 4; mt++) {
          float r = p.resid[row + mt*16 + l15];
          float v = (acc[nt][mt][reg] + bs[mt] + r)*sc[mt] + sh[mt];
          Tb[wv][mt][(quad*4 + reg)*17 + l15] = v;
        }
      }
      __syncthreads();
#pragma unroll
      for (int mt = 0; mt < 4; mt++)
#pragma unroll
        for (int reg = 0; reg < 4; reg++) {
          float v = Tb[wv][mt][l15*17 + quad*4 + reg];
          p.OutF[((size_t)(bb*p.M + m0 + mt*16 + quad*4 + reg))*NPT
                 + n0 + wv*WR + nt*16 + l15] = v;
        }
      __syncthreads();
    }
  }
}

template<int EPI, int NT>
__global__ __launch_bounds__(256)
void mgemm_kernel(MG p) { mgemm_body<EPI, NT>(p, blockIdx.x, blockIdx.y, blockIdx.z); }

// stage2 fused: [0,2048) knn_merge | [2048,2816) qkv GEMM (grid 32x12x2 linearized)
__global__ __launch_bounds__(256)
void stage2_kernel(const unsigned int* Pp, int* idx, MG pqkv) {
  int bi = blockIdx.x;
  if (bi < 2048) {
    knn_merge_body(Pp, idx, bi);
  } else {
    int i = bi - 2048;
    mgemm_body<0, 2>(pqkv, i & 31, (i >> 5) % 12, i / 384);
  }
}

// ---------------- fused attention v4: 4 points/block, shared weight reads ----------
__global__ __launch_bounds__(256, 4)
void attn_kernel(const unsigned short* __restrict__ qkv, const float4* __restrict__ w1f,
                 const float4* __restrict__ W2t, const float* __restrict__ xyz,
                 const int* __restrict__ idx, unsigned short* __restrict__ attn_b) {
  __shared__ float4 sw1[256];
  __shared__ float4 sw2[256];
  __shared__ int   sidx[4][16];
  __shared__ float srel[4][16][4];
  __shared__ float sbias[4][16][4];
  __shared__ float red[4][16*68];
  int tid = threadIdx.x;
  int bn0 = blockIdx.x * 4;
  int b   = bn0 >> 12;
  sw1[tid] = w1f[tid];
  sw2[tid] = W2t[tid];
  if (tid < 64) {
    int p = tid >> 4, kk = tid & 15;
    int bn = bn0 + p, n = bn & 4095;
    int j = idx[bn*16 + kk];
    sidx[p][kk] = j;
    const float* pb = xyz + (size_t)b * 3 * NPT;
    srel[p][kk][0] = pb[j]         - pb[n];
    srel[p][kk][1] = pb[NPT + j]   - pb[NPT + n];
    srel[p][kk][2] = pb[2*NPT + j] - pb[2*NPT + n];
  }
  __syncthreads();
  {  // ---- bias phase: 4 points per weight read ----
    int kk = tid >> 4, cs = tid & 15;
    float rx[4], ry[4], rz[4], h[4][4];
#pragma unroll
    for (int p = 0; p < 4; p++) {
      rx[p] = srel[p][kk][0]; ry[p] = srel[p][kk][1]; rz[p] = srel[p][kk][2];
#pragma unroll
      for (int q = 0; q < 4; q++) h[p][q] = 0.f;
    }
#pragma unroll
    for (int i = 0; i < 16; i++) {
      int c = cs*16 + ((i + cs) & 15);
      float4 w  = sw1[c];
      float4 w2 = sw2[c];
#pragma unroll
      for (int p = 0; p < 4; p++) {
        float t0 = fmaxf(fmaf(rx[p], w.x, fmaf(ry[p], w.y, fmaf(rz[p], w.z, w.w))), 0.f);
        h[p][0] = fmaf(t0, w2.x, h[p][0]); h[p][1] = fmaf(t0, w2.y, h[p][1]);
        h[p][2] = fmaf(t0, w2.z, h[p][2]); h[p][3] = fmaf(t0, w2.w, h[p][3]);
      }
    }
#pragma unroll
    for (int off = 1; off < 16; off <<= 1)
#pragma unroll
      for (int p = 0; p < 4; p++)
#pragma unroll
        for (int q = 0; q < 4; q++)
          h[p][q] += __shfl_xor(h[p][q], off, 64);
    if (cs == 0)
#pragma unroll
      for (int p = 0; p < 4; p++)
#pragma unroll
        for (int q = 0; q < 4; q++) sbias[p][kk][q] = h[p][q];
  }
  __syncthreads();
  // ---- attention phase: 4 points serial ----
  int wv   = tid >> 6;
  int lane = tid & 63;
  int k    = lane >> 2;
  int c4   = lane & 3;
  int ch0  = wv*64 + c4*16;
  size_t base = (size_t)(b*NPT) * 768;
#pragma unroll 1
  for (int p = 0; p < 4; p++) {
    int bn = bn0 + p;
    size_t rowq = (size_t)bn * 768;
    float qf[16];
    {
      uint4 q0 = *(const uint4*)(qkv + rowq + ch0);
      uint4 q1 = *(const uint4*)(qkv + rowq + ch0 + 8);
      up16(q0, q1, qf);
    }
    int j = sidx[p][k];
    float dot = 0.f;
    {
      const unsigned short* krow = qkv + base + (size_t)j*768 + 256 + ch0;
      uint4 k0 = *(const uint4*)(krow);
      uint4 k1 = *(const uint4*)(krow + 8);
      float kf[16];
      up16(k0, k1, kf);
#pragma unroll
      for (int i = 0; i < 16; i++) dot = fmaf(qf[i], kf[i], dot);
    }
    dot += __shfl_xor(dot, 1, 64);
    dot += __shfl_xor(dot, 2, 64);
    float logit = dot * 0.125f + sbias[p][k][wv];
    float mx = logit;
#pragma unroll
    for (int off = 4; off < 64; off <<= 1) mx = fmaxf(mx, __shfl_xor(mx, off, 64));
    float e = __expf(logit - mx);
    float ssum = e;
#pragma unroll
    for (int off = 4; off < 64; off <<= 1) ssum += __shfl_xor(ssum, off, 64);
    float w = e / ssum;
    {
      const unsigned short* vrow = qkv + base + (size_t)j*768 + 512 + ch0;
      uint4 v0 = *(const uint4*)(vrow);
      uint4 v1 = *(const uint4*)(vrow + 8);
      float vf[16];
      up16(v0, v1, vf);
      float* dst = &red[wv][k*68 + c4*16];
#pragma unroll
      for (int g = 0; g < 4; g++)
        ((float4*)dst)[g] = make_float4(w*vf[g*4], w*vf[g*4+1], w*vf[g*4+2], w*vf[g*4+3]);
    }
    __syncthreads();
    float o = 0.f;
#pragma unroll
    for (int kk2 = 0; kk2 < 16; kk2++) o += red[wv][kk2*68 + lane];
    attn_b[(size_t)bn*256 + wv*64 + lane] = f2b(o);
    __syncthreads();
  }
}

extern "C" void kernel_launch(void* const* d_in, const int* in_sizes, int n_in,
                              void* d_out, int out_size, void* d_ws, size_t ws_size,
                              hipStream_t stream) {
  const float* x     = (const float*)d_in[0];
  const float* xyz   = (const float*)d_in[1];
  const float* Wq    = (const float*)d_in[2];
  const float* Wkv   = (const float*)d_in[3];
  const float* Wproj = (const float*)d_in[4];
  const float* rp_w1 = (const float*)d_in[5];
  const float* rp_g  = (const float*)d_in[6];
  const float* rp_b  = (const float*)d_in[7];
  const float* rp_m  = (const float*)d_in[8];
  const float* rp_v  = (const float*)d_in[9];
  const float* rp_w2 = (const float*)d_in[10];
  const float* bn1_g = (const float*)d_in[11];
  const float* bn1_b = (const float*)d_in[12];
  const float* bn1_m = (const float*)d_in[13];
  const float* bn1_v = (const float*)d_in[14];
  const float* bn2_g = (const float*)d_in[15];
  const float* bn2_b = (const float*)d_in[16];
  const float* bn2_m = (const float*)d_in[17];
  const float* bn2_v = (const float*)d_in[18];
  const float* ffn_w1 = (const float*)d_in[19];
  const float* ffn_b1 = (const float*)d_in[20];
  const float* ffn_w2 = (const float*)d_in[21];
  const float* ffn_b2 = (const float*)d_in[22];

  char* ws = (char*)d_ws;
  // static region
  float4* w1f = (float4*)(ws + 0);                         //   4 KB
  float4* W2t = (float4*)(ws + 4096);                      //   4 KB
  int*    idx = (int*)  (ws + 8192);                       // 512 KB
  // reuse region A (32 MB): KNN scratch first, then post-attn tensors
  const size_t oA = 532480;
  unsigned int*   Pp     = (unsigned int*)(ws + oA);       // 16 MB u32 [B*N][512] keys
  unsigned short* attn_b = (unsigned short*)(ws + oA);                 //  4 MB bf16 [B][N][256]
  float*          x1f    = (float*)(ws + oA + (4u<<20));               //  8 MB fp32 [B][N][256]
  unsigned short* x1b    = (unsigned short*)(ws + oA + (12u<<20));     //  4 MB bf16 [B][N][256]
  unsigned short* h_b    = (unsigned short*)(ws + oA + (16u<<20));     // 16 MB bf16 [B][N][1024]
  // region B: weights + casted x + qkv
  const size_t oB = oA + (32u<<20);
  unsigned short* Wqkv_b  = (unsigned short*)(ws + oB);                // 384 KB [768][256]
  unsigned short* Wproj_b = (unsigned short*)(ws + oB + 393216);       // 128 KB
  unsigned short* W1_b    = (unsigned short*)(ws + oB + 524288);       // 512 KB
  unsigned short* W2_b    = (unsigned short*)(ws + oB + 1048576);      // 512 KB
  unsigned short* xb      = (unsigned short*)(ws + oB + 1572864);      //   4 MB bf16 [B][N][256]
  float*          xf      = (float*)(ws + oB + 1572864 + (4u<<20));    //   8 MB fp32 [B][N][256]
  unsigned short* qkv     = (unsigned short*)(ws + oB + 1572864 + (12u<<20)); // 12 MB bf16 [B][N][768]

  stage1_kernel<<<4609, 256, 0, stream>>>(x, xb, xf, xyz, Pp,
                                          Wq, Wkv, Wproj, ffn_w1, ffn_w2,
                                          Wqkv_b, Wproj_b, W1_b, W2_b,
                                          rp_w1, rp_g, rp_b, rp_m, rp_v, rp_w2,
                                          w1f, W2t);

  MG pqkv = {xb, Wqkv_b, 256, 768, qkv, nullptr,
             nullptr, nullptr, nullptr, nullptr, nullptr, nullptr};
  stage2_kernel<<<2816, 256, 0, stream>>>(Pp, idx, pqkv);

  attn_kernel<<<(BB*NPT)/4, 256, 0, stream>>>(qkv, w1f, W2t, xyz, idx, attn_b);

  MG pproj = {attn_b, Wproj_b, 256, 256, x1b, x1f,
              nullptr, xf, bn1_g, bn1_b, bn1_m, bn1_v};
  mgemm_kernel<2, 1><<<dim3(64, 4, BB), 256, 0, stream>>>(pproj);

  MG pf1 = {x1b, W1_b, 256, 1024, h_b, nullptr,
            ffn_b1, nullptr, nullptr, nullptr, nullptr, nullptr};
  mgemm_kernel<1, 2><<<dim3(32, 16, BB), 256, 0, stream>>>(pf1);

  MG pf2 = {h_b, W2_b, 1024, 256, nullptr, (float*)d_out,
            ffn_b2, x1f, bn2_g, bn2_b, bn2_m, bn2_v};
  mgemm_kernel<3, 1><<<dim3(64, 4, BB), 256, 0, stream>>>(pf2);
}

// Round 4
// 194.760 us; speedup vs baseline: 1.2926x; 1.1402x over previous
//
#include <hip/hip_runtime.h>
#include <math.h>

#define BB   2
#define CC   256
#define NPT  4096
#define HH   4
#define DD   64
#define KNN  16
#define EPSBN 1e-5f

typedef __attribute__((ext_vector_type(8))) short short8;
typedef __attribute__((ext_vector_type(4))) float f32x4;

typedef __attribute__((address_space(3))) unsigned int lds_u32;
typedef const __attribute__((address_space(1))) unsigned int glb_u32;
__device__ __forceinline__ void gl_lds16(const void* g, void* l) {
  __builtin_amdgcn_global_load_lds((glb_u32*)g, (lds_u32*)l, 16, 0, 0);
}

__device__ __forceinline__ unsigned short f2b(float f) {
  union { float f; unsigned int u; } v; v.f = f;
  unsigned int r = (v.u + 0x7FFFu + ((v.u >> 16) & 1u)) >> 16;
  return (unsigned short)r;
}
__device__ __forceinline__ void up2(unsigned int u, float& a, float& b) {
  union { unsigned int x; float f; } lo, hi;
  lo.x = u << 16; hi.x = u & 0xffff0000u;
  a = lo.f; b = hi.f;
}
__device__ __forceinline__ void up16(uint4 u0, uint4 u1, float* f) {
  up2(u0.x, f[0], f[1]);  up2(u0.y, f[2], f[3]);
  up2(u0.z, f[4], f[5]);  up2(u0.w, f[6], f[7]);
  up2(u1.x, f[8], f[9]);  up2(u1.y, f[10], f[11]);
  up2(u1.z, f[12], f[13]); up2(u1.w, f[14], f[15]);
}

// v_med3_u32: 1-op sorted-list insert step (no builtin on gfx950 -> inline asm)
__device__ __forceinline__ unsigned int med3u(unsigned int a, unsigned int b, unsigned int c) {
  unsigned int d;
  asm("v_med3_u32 %0, %1, %2, %3" : "=v"(d) : "v"(a), "v"(b), "v"(c));
  return d;
}
__device__ __forceinline__ void ce32(unsigned int& x, unsigned int& y) {
  unsigned int a = min(x, y), b = max(x, y);
  x = a; y = b;
}

// ================= stage 1 bodies (independent work, fused dispatch) =================
__device__ __forceinline__
void wcast_body(const float* Wq, const float* Wkv, const float* Wp,
                const float* W1, const float* W2,
                unsigned short* oQKV, unsigned short* oP,
                unsigned short* o1, unsigned short* o2,
                const float* rp_w1, const float* rp_g, const float* rp_b,
                const float* rp_m, const float* rp_v, const float* rp_w2,
                float4* w1f, float4* W2t, int blk) {
  if (blk == 3072) {            // prep: fold rp BN into w1, reduce rp_w2 over heads
    int c = threadIdx.x;
    float s  = rp_g[c] / sqrtf(rp_v[c] + EPSBN);
    float b0 = rp_b[c] - rp_m[c] * s;
    w1f[c] = make_float4(rp_w1[c*3+0]*s, rp_w1[c*3+1]*s, rp_w1[c*3+2]*s, b0);
    float a0=0.f,a1=0.f,a2=0.f,a3=0.f;
    for (int o = 0; o < 64; o++) {
      a0 += rp_w2[(      o)*CC + c];
      a1 += rp_w2[( 64 + o)*CC + c];
      a2 += rp_w2[(128 + o)*CC + c];
      a3 += rp_w2[(192 + o)*CC + c];
    }
    W2t[c] = make_float4(a0,a1,a2,a3);
    return;
  }
  int i = blk * 256 + threadIdx.x;          // 786432 total
  if (i < 65536)        oQKV[i] = f2b(Wq[i]);
  else if (i < 196608)  oQKV[i] = f2b(Wkv[i - 65536]);
  else if (i < 262144)  oP[i - 196608] = f2b(Wp[i - 196608]);
  else if (i < 524288)  o1[i - 262144] = f2b(W1[i - 262144]);
  else                  o2[i - 524288] = f2b(W2[i - 524288]);
}

__device__ __forceinline__
void xcast_body(const float* x, unsigned short* xb, float* xf,
                float (*T)[65], int bx, int by, int bz) {
  int n0 = bx * 64, c0 = by * 64, bb = bz;
  int tid = threadIdx.x;
  {
    int crow = tid >> 2, ns = (tid & 3) * 16;
    const float* xp = x + ((size_t)(bb*CC + c0 + crow))*NPT + n0 + ns;
#pragma unroll
    for (int i = 0; i < 4; i++) {
      float4 v = ((const float4*)xp)[i];
      T[crow][ns + i*4 + 0] = v.x; T[crow][ns + i*4 + 1] = v.y;
      T[crow][ns + i*4 + 2] = v.z; T[crow][ns + i*4 + 3] = v.w;
    }
  }
  __syncthreads();
  {
    int nrow = tid >> 2, cs = (tid & 3) * 16;
    float vals[16];
#pragma unroll
    for (int i = 0; i < 16; i++) vals[i] = T[cs + i][nrow];
    size_t orow = ((size_t)(bb*NPT + n0 + nrow))*CC + c0 + cs;
#pragma unroll
    for (int i = 0; i < 4; i++)
      *(float4*)&xf[orow + i*4] = make_float4(vals[i*4], vals[i*4+1], vals[i*4+2], vals[i*4+3]);
    unsigned short us[16];
#pragma unroll
    for (int i = 0; i < 16; i++) us[i] = f2b(vals[i]);
    *(uint4*)&xb[orow]     = *(const uint4*)&us[0];
    *(uint4*)&xb[orow + 8] = *(const uint4*)&us[8];
  }
}

// KNN stage 1: packed-u32 sorted-insert via v_med3_u32 — 1 op/position.
// Insertion into ascending list k0..k15 (applied DESCENDING so old k_{i-1} is read):
//   k_i' = med3(key, k_{i-1}, k_i);  k0' = min(key, k0)
// Keys are (non-negative float bits & ~0x1FF) | within-512-chunk index, so u32
// order == (distance, index) order and sentinels 0xFFFFFFFF sort last.
#define MPROC(M4, MI) { \
    float nd = fmaf(qx2, (M4).x, fmaf(qy2, (M4).y, fmaf(qz2, (M4).z, (M4).w + qsq))); \
    nd = fmaxf(nd, 0.f); \
    unsigned int key = (__float_as_uint(nd) & 0xFFFFFE00u) | (unsigned int)(MI); \
    k15 = med3u(key, k14, k15); k14 = med3u(key, k13, k14); \
    k13 = med3u(key, k12, k13); k12 = med3u(key, k11, k12); \
    k11 = med3u(key, k10, k11); k10 = med3u(key, k9,  k10); \
    k9  = med3u(key, k8,  k9 ); k8  = med3u(key, k7,  k8 ); \
    k7  = med3u(key, k6,  k7 ); k6  = med3u(key, k5,  k6 ); \
    k5  = med3u(key, k4,  k5 ); k4  = med3u(key, k3,  k4 ); \
    k3  = med3u(key, k2,  k3 ); k2  = med3u(key, k1,  k2 ); \
    k1  = med3u(key, k0,  k1 ); k0  = min(key, k0); }

// Block stages one 512-pt chunk; each of 4 waves scans a 128-quarter for the same
// 64 queries, then TWO in-LDS butterfly rounds (partner ^1, ^2) collapse the 4
// partial lists into the chunk's true top-16 (u32 keys, same chunk -> same
// tie-break space). Wave 0 writes -> Pp is 8 lists/query = 4 MB (was 16).
__device__ __forceinline__
void knn_partial_body(const float* xyz, unsigned int* Pp, char* smem,
                      int s, int qg, int b) {
  float4* sp = (float4*)smem;
  const float* base = xyz + (size_t)b * 3 * NPT;
  int c0 = s * 512;
  for (int i = threadIdx.x; i < 512; i += 256) {
    float mx = base[c0 + i], my = base[NPT + c0 + i], mz = base[2*NPT + c0 + i];
    sp[i] = make_float4(mx, my, mz, mx*mx + my*my + mz*mz);
  }
  int lane = threadIdx.x & 63;
  int wv   = threadIdx.x >> 6;
  int qn   = qg * 64 + lane;
  float qx = base[qn], qy = base[NPT + qn], qz = base[2*NPT + qn];
  float qsq = qx*qx + qy*qy + qz*qz;
  float qx2 = -2.f*qx, qy2 = -2.f*qy, qz2 = -2.f*qz;
  __syncthreads();

  unsigned int k0=0xFFFFFFFFu,k1=0xFFFFFFFFu,k2=0xFFFFFFFFu,k3=0xFFFFFFFFu,
               k4=0xFFFFFFFFu,k5=0xFFFFFFFFu,k6=0xFFFFFFFFu,k7=0xFFFFFFFFu,
               k8=0xFFFFFFFFu,k9=0xFFFFFFFFu,k10=0xFFFFFFFFu,k11=0xFFFFFFFFu,
               k12=0xFFFFFFFFu,k13=0xFFFFFFFFu,k14=0xFFFFFFFFu,k15=0xFFFFFFFFu;

  int sb = wv * 128;            // wave's sub-chunk; payload = within-512 index
  for (int mm = 0; mm < 128; mm += 4) {
    float4 a4 = sp[sb+mm], bq = sp[sb+mm+1], cq = sp[sb+mm+2], dq = sp[sb+mm+3];
    MPROC(a4, sb+mm)
    MPROC(bq, sb+mm+1)
    MPROC(cq, sb+mm+2)
    MPROC(dq, sb+mm+3)
  }

  // ---- in-block merge: 4 sorted 16-lists (same chunk) -> chunk top-16 ----
  unsigned int a[16] = {k0,k1,k2,k3,k4,k5,k6,k7,k8,k9,k10,k11,k12,k13,k14,k15};
  unsigned int* L = (unsigned int*)smem;        // reuses sp space (stride 17: conflict-free)
  int me = (wv*64 + lane)*17;
  __syncthreads();                               // sp reads done
#pragma unroll
  for (int pw = 1; pw <= 2; pw <<= 1) {
#pragma unroll
    for (int i = 0; i < 16; i++) L[me + i] = a[i];
    __syncthreads();
    int pb = ((wv ^ pw)*64 + lane)*17;
    unsigned int t[16];
#pragma unroll
    for (int i = 0; i < 16; i++) t[i] = min(a[i], L[pb + 15 - i]);
#pragma unroll
    for (int d = 8; d >= 1; d >>= 1)
#pragma unroll
      for (int i = 0; i < 16; i++)
        if ((i & d) == 0) ce32(t[i], t[i + d]);
#pragma unroll
    for (int i = 0; i < 16; i++) a[i] = t[i];
    __syncthreads();                             // before next round's L overwrite
  }
  if (wv == 0) {
    int gq = b * NPT + qn;
    uint4* out = (uint4*)(Pp + (size_t)gq * 128 + s * 16);
    out[0] = make_uint4(a[0],  a[1],  a[2],  a[3]);
    out[1] = make_uint4(a[4],  a[5],  a[6],  a[7]);
    out[2] = make_uint4(a[8],  a[9],  a[10], a[11]);
    out[3] = make_uint4(a[12], a[13], a[14], a[15]);
  }
}

// stage1 fused dispatch: [0,1024) knn | [1024,1536) xcast | [1536,4609) wcast.
// knn FIRST so the VALU-bound tail starts at t=0 and the memory-bound cast blocks
// co-schedule under it. LDS pool: max(xcast 16640, knn sp 8192 -> L 17400) = 17408.
__global__ __launch_bounds__(256) __attribute__((amdgpu_waves_per_eu(1, 4)))
void stage1_kernel(const float* x, unsigned short* xb, float* xf,
                   const float* xyz, unsigned int* Pp,
                   const float* Wq, const float* Wkv, const float* Wp,
                   const float* W1, const float* W2,
                   unsigned short* oQKV, unsigned short* oP,
                   unsigned short* o1, unsigned short* o2,
                   const float* rp_w1, const float* rp_g, const float* rp_b,
                   const float* rp_m, const float* rp_v, const float* rp_w2,
                   float4* w1f, float4* W2t) {
  __shared__ __align__(16) char smem[17408];
  int bi = blockIdx.x;
  if (bi < 1024) {
    knn_partial_body(xyz, Pp, smem, bi & 7, (bi >> 3) & 63, bi >> 9);
  } else if (bi < 1536) {
    int i = bi - 1024;
    xcast_body(x, xb, xf, (float(*)[65])smem, i & 63, (i >> 6) & 3, i >> 8);
  } else {
    wcast_body(Wq, Wkv, Wp, W1, W2, oQKV, oP, o1, o2,
               rp_w1, rp_g, rp_b, rp_m, rp_v, rp_w2, w1f, W2t, bi - 1536);
  }
}

// ================= stage 2: qkv GEMM + knn_merge (independent, fused) ================
// Merge v3: lane = (query, chunk) — 8 queries/wave, each query's 8 sorted chunk-
// lists live in 8 adjacent lanes (16 entries each, 64B coalesced load). 3 butterfly
// rounds m=1,2,4 of "lowest-16 of two sorted-16s" (u64 keys = maskedDist<<32|gidx
// for exact global tie-break), bitonic re-sort except last round (set suffices:
// downstream softmax+sum is permutation-invariant, bias pairs with its own idx).
__device__ __forceinline__ unsigned long long min64(unsigned long long a, unsigned long long b) {
  return a < b ? a : b;
}
__device__ __forceinline__ void ce64(unsigned long long& x, unsigned long long& y) {
  unsigned long long a = x, b = y;
  bool lt = a < b;
  x = lt ? a : b;
  y = lt ? b : a;
}
__device__ __forceinline__
void knn_merge_body(const unsigned int* Pp, int* idx_out, int blk) {
  int wv   = threadIdx.x >> 6;
  int lane = threadIdx.x & 63;
  int gq   = (blk*4 + wv)*8 + (lane >> 3);
  int s    = lane & 7;
  const uint4* src = (const uint4*)(Pp + (size_t)gq * 128 + s * 16);
  uint4 u0 = src[0], u1 = src[1], u2 = src[2], u3 = src[3];
  unsigned int gb = (unsigned int)s * 512u;
  unsigned long long a[16];
  {
    unsigned int ks[16] = {u0.x,u0.y,u0.z,u0.w, u1.x,u1.y,u1.z,u1.w,
                           u2.x,u2.y,u2.z,u2.w, u3.x,u3.y,u3.z,u3.w};
#pragma unroll
    for (int t = 0; t < 16; t++)
      a[t] = ((unsigned long long)(ks[t] & 0xFFFFFE00u) << 32) | (gb + (ks[t] & 0x1FFu));
  }
#pragma unroll
  for (int r = 0; r < 3; r++) {
    const int m = 1 << r;
    unsigned long long t[16];
#pragma unroll
    for (int i = 0; i < 16; i++) {
      unsigned long long pb = __shfl_xor(a[15 - i], m, 64);
      t[i] = min64(a[i], pb);
    }
    if (r < 2) {
#pragma unroll
      for (int d = 8; d >= 1; d >>= 1)
#pragma unroll
        for (int i = 0; i < 16; i++)
          if ((i & d) == 0) ce64(t[i], t[i + d]);
    }
#pragma unroll
    for (int i = 0; i < 16; i++) a[i] = t[i];
  }
  if (s == 0) {
    int4* o = (int4*)(idx_out + gq*16);
    o[0] = make_int4((int)(unsigned)a[0],  (int)(unsigned)a[1],
                     (int)(unsigned)a[2],  (int)(unsigned)a[3]);
    o[1] = make_int4((int)(unsigned)a[4],  (int)(unsigned)a[5],
                     (int)(unsigned)a[6],  (int)(unsigned)a[7]);
    o[2] = make_int4((int)(unsigned)a[8],  (int)(unsigned)a[9],
                     (int)(unsigned)a[10], (int)(unsigned)a[11]);
    o[3] = make_int4((int)(unsigned)a[12], (int)(unsigned)a[13],
                     (int)(unsigned)a[14], (int)(unsigned)a[15]);
  }
}

// ------- MFMA bf16 GEMM v3: NT-templated N-tile (NT*64 rows) ------------------------
struct MG {
  const unsigned short* A; const unsigned short* Wt; int K; int M;
  unsigned short* OutB; float* OutF;
  const float* bias; const float* resid;
  const float* bng; const float* bnb; const float* bnm; const float* bnv;
};

template<int EPI, int NT>
__device__ __forceinline__ void mgemm_body(const MG& p, int bx, int by, int bz) {
  __shared__ unsigned short As[NT*64*64];
  __shared__ unsigned short Bs[64*64];
  const int tid  = threadIdx.x;
  const int bb   = bz;
  const int n0   = bx * (NT*64);
  const int m0   = by * 64;
  const int lane = tid & 63;
  const int wv   = tid >> 6;
  const int l15  = lane & 15;
  const int quad = lane >> 4;
  const int K    = p.K;
  const int WR   = NT*16;                   // wave row span

  f32x4 acc[NT][4];
#pragma unroll
  for (int i = 0; i < NT; i++)
#pragma unroll
    for (int j = 0; j < 4; j++) acc[i][j] = (f32x4){0.f, 0.f, 0.f, 0.f};

  const int srow = wv*8 + (lane >> 3);
  const int pseg = lane & 7;
  const unsigned short* Abase = p.A  + (size_t)bb*NPT*K;

  for (int c0 = 0; c0 < K; c0 += 64) {
#pragma unroll
    for (int t = 0; t < NT*2; t++) {
      int row = t*32 + srow;
      int ls  = pseg ^ (row & 7);
      gl_lds16(Abase + (size_t)(n0 + row)*K + c0 + ls*8,
               &As[wv*512 + t*2048 + lane*8]);
    }
#pragma unroll
    for (int t = 0; t < 2; t++) {
      int row = t*32 + srow;
      int ls  = pseg ^ (row & 7);
      gl_lds16(p.Wt + (size_t)(m0 + row)*K + c0 + ls*8,
               &Bs[wv*512 + t*2048 + lane*8]);
    }
    __syncthreads();
    short8 bf[4][2];
#pragma unroll
    for (int mt = 0; mt < 4; mt++)
#pragma unroll
      for (int kk = 0; kk < 2; kk++) {
        int row = mt*16 + l15;
        int ps  = (kk*4 + quad) ^ (row & 7);
        bf[mt][kk] = *(const short8*)&Bs[row*64 + ps*8];
      }
#pragma unroll
    for (int nt = 0; nt < NT; nt++)
#pragma unroll
      for (int kk = 0; kk < 2; kk++) {
        int row = wv*WR + nt*16 + l15;
        int ps  = (kk*4 + quad) ^ (row & 7);
        short8 af = *(const short8*)&As[row*64 + ps*8];
#pragma unroll
        for (int mt = 0; mt < 4; mt++)
          acc[nt][mt] = __builtin_amdgcn_mfma_f32_16x16x32_bf16(af, bf[mt][kk], acc[nt][mt], 0, 0, 0);
      }
    __syncthreads();
  }

  if (EPI == 0 || EPI == 1) {
    float bs[4];
#pragma unroll
    for (int mt = 0; mt < 4; mt++)
      bs[mt] = (EPI == 1) ? p.bias[m0 + mt*16 + l15] : 0.f;
#pragma unroll
    for (int nt = 0; nt < NT; nt++)
#pragma unroll
      for (int reg = 0; reg < 4; reg++) {
        size_t row = ((size_t)(bb*NPT + n0 + wv*WR + nt*16 + quad*4 + reg))*p.M + m0;
#pragma unroll
        for (int mt = 0; mt < 4; mt++) {
          float v = acc[nt][mt][reg] + bs[mt];
          if (EPI == 1) v = fmaxf(v, 0.f);
          p.OutB[row + mt*16 + l15] = f2b(v);
        }
      }
  } else if (EPI == 2) {
    float sc[4], sh[4];
#pragma unroll
    for (int mt = 0; mt < 4; mt++) {
      int m = m0 + mt*16 + l15;
      float s = p.bng[m] / sqrtf(p.bnv[m] + EPSBN);
      sc[mt] = s; sh[mt] = p.bnb[m] - p.bnm[m]*s;
    }
#pragma unroll
    for (int nt = 0; nt < NT; nt++)
#pragma unroll
      for (int reg = 0; reg < 4; reg++) {
        size_t row = ((size_t)(bb*NPT + n0 + wv*WR + nt*16 + quad*4 + reg))*p.M + m0;
#pragma unroll
        for (int mt = 0; mt < 4; mt++) {
          float r = p.resid[row + mt*16 + l15];
          float v = (acc[nt][mt][reg] + r)*sc[mt] + sh[mt];
          p.OutF[row + mt*16 + l15] = v;
          p.OutB[row + mt*16 + l15] = f2b(v);
        }
      }
  } else {  // EPI == 3
    __shared__ float Tb[4][4][16*17];
    float sc[4], sh[4], bs[4];
#pragma unroll
    for (int mt = 0; mt < 4; mt++) {
      int m = m0 + mt*16 + l15;
      float s = p.bng[m] / sqrtf(p.bnv[m] + EPSBN);
      sc[mt] = s; sh[mt] = p.bnb[m] - p.bnm[m]*s;
      bs[mt] = p.bias[m];
    }
#pragma unroll
    for (int nt = 0; nt < NT; nt++) {
#pragma unroll
      for (int reg = 0; reg < 4; reg++) {
        size_t row = ((size_t)(bb*NPT + n0 + wv*WR + nt*16 + quad*4 + reg))*p.M + m0;
#pragma unroll
        for (int mt = 0; mt < 4; mt++) {
          float r = p.resid[row + mt*16 + l15];
          float v = (acc[nt][mt][reg] + bs[mt] + r)*sc[mt] + sh[mt];
          Tb[wv][mt][(quad*4 + reg)*17 + l15] = v;
        }
      }
      __syncthreads();
#pragma unroll
      for (int mt = 0; mt < 4; mt++)
#pragma unroll
        for (int reg = 0; reg < 4; reg++) {
          float v = Tb[wv][mt][l15*17 + quad*4 + reg];
          p.OutF[((size_t)(bb*p.M + m0 + mt*16 + quad*4 + reg))*NPT
                 + n0 + wv*WR + nt*16 + l15] = v;
        }
      __syncthreads();
    }
  }
}

template<int EPI, int NT>
__global__ __launch_bounds__(256)
void mgemm_kernel(MG p) { mgemm_body<EPI, NT>(p, blockIdx.x, blockIdx.y, blockIdx.z); }

// stage2 fused: [0,768) qkv GEMM (long poles first) | [768,1024) knn_merge
__global__ __launch_bounds__(256)
void stage2_kernel(const unsigned int* Pp, int* idx, MG pqkv) {
  int bi = blockIdx.x;
  if (bi < 768) {
    mgemm_body<0, 2>(pqkv, bi & 31, (bi >> 5) % 12, bi / 384);
  } else {
    knn_merge_body(Pp, idx, bi - 768);
  }
}

// ---------------- fused attention v4: 4 points/block, shared weight reads ----------
__global__ __launch_bounds__(256, 4)
void attn_kernel(const unsigned short* __restrict__ qkv, const float4* __restrict__ w1f,
                 const float4* __restrict__ W2t, const float* __restrict__ xyz,
                 const int* __restrict__ idx, unsigned short* __restrict__ attn_b) {
  __shared__ float4 sw1[256];
  __shared__ float4 sw2[256];
  __shared__ int   sidx[4][16];
  __shared__ float srel[4][16][4];
  __shared__ float sbias[4][16][4];
  __shared__ float red[4][16*68];
  int tid = threadIdx.x;
  int bn0 = blockIdx.x * 4;
  int b   = bn0 >> 12;
  sw1[tid] = w1f[tid];
  sw2[tid] = W2t[tid];
  if (tid < 64) {
    int p = tid >> 4, kk = tid & 15;
    int bn = bn0 + p, n = bn & 4095;
    int j = idx[bn*16 + kk];
    sidx[p][kk] = j;
    const float* pb = xyz + (size_t)b * 3 * NPT;
    srel[p][kk][0] = pb[j]         - pb[n];
    srel[p][kk][1] = pb[NPT + j]   - pb[NPT + n];
    srel[p][kk][2] = pb[2*NPT + j] - pb[2*NPT + n];
  }
  __syncthreads();
  {  // ---- bias phase: 4 points per weight read ----
    int kk = tid >> 4, cs = tid & 15;
    float rx[4], ry[4], rz[4], h[4][4];
#pragma unroll
    for (int p = 0; p < 4; p++) {
      rx[p] = srel[p][kk][0]; ry[p] = srel[p][kk][1]; rz[p] = srel[p][kk][2];
#pragma unroll
      for (int q = 0; q < 4; q++) h[p][q] = 0.f;
    }
#pragma unroll
    for (int i = 0; i < 16; i++) {
      int c = cs*16 + ((i + cs) & 15);
      float4 w  = sw1[c];
      float4 w2 = sw2[c];
#pragma unroll
      for (int p = 0; p < 4; p++) {
        float t0 = fmaxf(fmaf(rx[p], w.x, fmaf(ry[p], w.y, fmaf(rz[p], w.z, w.w))), 0.f);
        h[p][0] = fmaf(t0, w2.x, h[p][0]); h[p][1] = fmaf(t0, w2.y, h[p][1]);
        h[p][2] = fmaf(t0, w2.z, h[p][2]); h[p][3] = fmaf(t0, w2.w, h[p][3]);
      }
    }
#pragma unroll
    for (int off = 1; off < 16; off <<= 1)
#pragma unroll
      for (int p = 0; p < 4; p++)
#pragma unroll
        for (int q = 0; q < 4; q++)
          h[p][q] += __shfl_xor(h[p][q], off, 64);
    if (cs == 0)
#pragma unroll
      for (int p = 0; p < 4; p++)
#pragma unroll
        for (int q = 0; q < 4; q++) sbias[p][kk][q] = h[p][q];
  }
  __syncthreads();
  // ---- attention phase: 4 points serial ----
  int wv   = tid >> 6;
  int lane = tid & 63;
  int k    = lane >> 2;
  int c4   = lane & 3;
  int ch0  = wv*64 + c4*16;
  size_t base = (size_t)(b*NPT) * 768;
#pragma unroll 1
  for (int p = 0; p < 4; p++) {
    int bn = bn0 + p;
    size_t rowq = (size_t)bn * 768;
    float qf[16];
    {
      uint4 q0 = *(const uint4*)(qkv + rowq + ch0);
      uint4 q1 = *(const uint4*)(qkv + rowq + ch0 + 8);
      up16(q0, q1, qf);
    }
    int j = sidx[p][k];
    float dot = 0.f;
    {
      const unsigned short* krow = qkv + base + (size_t)j*768 + 256 + ch0;
      uint4 k0 = *(const uint4*)(krow);
      uint4 k1 = *(const uint4*)(krow + 8);
      float kf[16];
      up16(k0, k1, kf);
#pragma unroll
      for (int i = 0; i < 16; i++) dot = fmaf(qf[i], kf[i], dot);
    }
    dot += __shfl_xor(dot, 1, 64);
    dot += __shfl_xor(dot, 2, 64);
    float logit = dot * 0.125f + sbias[p][k][wv];
    float mx = logit;
#pragma unroll
    for (int off = 4; off < 64; off <<= 1) mx = fmaxf(mx, __shfl_xor(mx, off, 64));
    float e = __expf(logit - mx);
    float ssum = e;
#pragma unroll
    for (int off = 4; off < 64; off <<= 1) ssum += __shfl_xor(ssum, off, 64);
    float w = e / ssum;
    {
      const unsigned short* vrow = qkv + base + (size_t)j*768 + 512 + ch0;
      uint4 v0 = *(const uint4*)(vrow);
      uint4 v1 = *(const uint4*)(vrow + 8);
      float vf[16];
      up16(v0, v1, vf);
      float* dst = &red[wv][k*68 + c4*16];
#pragma unroll
      for (int g = 0; g < 4; g++)
        ((float4*)dst)[g] = make_float4(w*vf[g*4], w*vf[g*4+1], w*vf[g*4+2], w*vf[g*4+3]);
    }
    __syncthreads();
    float o = 0.f;
#pragma unroll
    for (int kk2 = 0; kk2 < 16; kk2++) o += red[wv][kk2*68 + lane];
    attn_b[(size_t)bn*256 + wv*64 + lane] = f2b(o);
    __syncthreads();
  }
}

extern "C" void kernel_launch(void* const* d_in, const int* in_sizes, int n_in,
                              void* d_out, int out_size, void* d_ws, size_t ws_size,
                              hipStream_t stream) {
  const float* x     = (const float*)d_in[0];
  const float* xyz   = (const float*)d_in[1];
  const float* Wq    = (const float*)d_in[2];
  const float* Wkv   = (const float*)d_in[3];
  const float* Wproj = (const float*)d_in[4];
  const float* rp_w1 = (const float*)d_in[5];
  const float* rp_g  = (const float*)d_in[6];
  const float* rp_b  = (const float*)d_in[7];
  const float* rp_m  = (const float*)d_in[8];
  const float* rp_v  = (const float*)d_in[9];
  const float* rp_w2 = (const float*)d_in[10];
  const float* bn1_g = (const float*)d_in[11];
  const float* bn1_b = (const float*)d_in[12];
  const float* bn1_m = (const float*)d_in[13];
  const float* bn1_v = (const float*)d_in[14];
  const float* bn2_g = (const float*)d_in[15];
  const float* bn2_b = (const float*)d_in[16];
  const float* bn2_m = (const float*)d_in[17];
  const float* bn2_v = (const float*)d_in[18];
  const float* ffn_w1 = (const float*)d_in[19];
  const float* ffn_b1 = (const float*)d_in[20];
  const float* ffn_w2 = (const float*)d_in[21];
  const float* ffn_b2 = (const float*)d_in[22];

  char* ws = (char*)d_ws;
  // static region
  float4* w1f = (float4*)(ws + 0);                         //   4 KB
  float4* W2t = (float4*)(ws + 4096);                      //   4 KB
  int*    idx = (int*)  (ws + 8192);                       // 512 KB
  // reuse region A (32 MB): KNN scratch first, then post-attn tensors
  const size_t oA = 532480;
  unsigned int*   Pp     = (unsigned int*)(ws + oA);       // 4 MB u32 [B*N][128] keys
  unsigned short* attn_b = (unsigned short*)(ws + oA);                 //  4 MB bf16 [B][N][256]
  float*          x1f    = (float*)(ws + oA + (4u<<20));               //  8 MB fp32 [B][N][256]
  unsigned short* x1b    = (unsigned short*)(ws + oA + (12u<<20));     //  4 MB bf16 [B][N][256]
  unsigned short* h_b    = (unsigned short*)(ws + oA + (16u<<20));     // 16 MB bf16 [B][N][1024]
  // region B: weights + casted x + qkv
  const size_t oB = oA + (32u<<20);
  unsigned short* Wqkv_b  = (unsigned short*)(ws + oB);                // 384 KB [768][256]
  unsigned short* Wproj_b = (unsigned short*)(ws + oB + 393216);       // 128 KB
  unsigned short* W1_b    = (unsigned short*)(ws + oB + 524288);       // 512 KB
  unsigned short* W2_b    = (unsigned short*)(ws + oB + 1048576);      // 512 KB
  unsigned short* xb      = (unsigned short*)(ws + oB + 1572864);      //   4 MB bf16 [B][N][256]
  float*          xf      = (float*)(ws + oB + 1572864 + (4u<<20));    //   8 MB fp32 [B][N][256]
  unsigned short* qkv     = (unsigned short*)(ws + oB + 1572864 + (12u<<20)); // 12 MB bf16 [B][N][768]

  stage1_kernel<<<4609, 256, 0, stream>>>(x, xb, xf, xyz, Pp,
                                          Wq, Wkv, Wproj, ffn_w1, ffn_w2,
                                          Wqkv_b, Wproj_b, W1_b, W2_b,
                                          rp_w1, rp_g, rp_b, rp_m, rp_v, rp_w2,
                                          w1f, W2t);

  MG pqkv = {xb, Wqkv_b, 256, 768, qkv, nullptr,
             nullptr, nullptr, nullptr, nullptr, nullptr, nullptr};
  stage2_kernel<<<1024, 256, 0, stream>>>(Pp, idx, pqkv);

  attn_kernel<<<(BB*NPT)/4, 256, 0, stream>>>(qkv, w1f, W2t, xyz, idx, attn_b);

  MG pproj = {attn_b, Wproj_b, 256, 256, x1b, x1f,
              nullptr, xf, bn1_g, bn1_b, bn1_m, bn1_v};
  mgemm_kernel<2, 1><<<dim3(64, 4, BB), 256, 0, stream>>>(pproj);

  MG pf1 = {x1b, W1_b, 256, 1024, h_b, nullptr,
            ffn_b1, nullptr, nullptr, nullptr, nullptr, nullptr};
  mgemm_kernel<1, 2><<<dim3(32, 16, BB), 256, 0, stream>>>(pf1);

  MG pf2 = {h_b, W2_b, 1024, 256, nullptr, (float*)d_out,
            ffn_b2, x1f, bn2_g, bn2_b, bn2_m, bn2_v};
  mgemm_kernel<3, 1><<<dim3(64, 4, BB), 256, 0, stream>>>(pf2);
}

// Round 6
// 193.447 us; speedup vs baseline: 1.3014x; 1.0068x over previous
//
#include <hip/hip_runtime.h>
#include <math.h>

#define BB   2
#define CC   256
#define NPT  4096
#define HH   4
#define DD   64
#define KNN  16
#define EPSBN 1e-5f

typedef __attribute__((ext_vector_type(8))) short short8;
typedef __attribute__((ext_vector_type(4))) float f32x4;

typedef __attribute__((address_space(3))) unsigned int lds_u32;
typedef const __attribute__((address_space(1))) unsigned int glb_u32;
__device__ __forceinline__ void gl_lds16(const void* g, void* l) {
  __builtin_amdgcn_global_load_lds((glb_u32*)g, (lds_u32*)l, 16, 0, 0);
}

__device__ __forceinline__ unsigned short f2b(float f) {
  union { float f; unsigned int u; } v; v.f = f;
  unsigned int r = (v.u + 0x7FFFu + ((v.u >> 16) & 1u)) >> 16;
  return (unsigned short)r;
}
__device__ __forceinline__ void up2(unsigned int u, float& a, float& b) {
  union { unsigned int x; float f; } lo, hi;
  lo.x = u << 16; hi.x = u & 0xffff0000u;
  a = lo.f; b = hi.f;
}
__device__ __forceinline__ void up16(uint4 u0, uint4 u1, float* f) {
  up2(u0.x, f[0], f[1]);  up2(u0.y, f[2], f[3]);
  up2(u0.z, f[4], f[5]);  up2(u0.w, f[6], f[7]);
  up2(u1.x, f[8], f[9]);  up2(u1.y, f[10], f[11]);
  up2(u1.z, f[12], f[13]); up2(u1.w, f[14], f[15]);
}

// v_med3_u32: 1-op sorted-list insert step (no builtin on gfx950 -> inline asm)
__device__ __forceinline__ unsigned int med3u(unsigned int a, unsigned int b, unsigned int c) {
  unsigned int d;
  asm("v_med3_u32 %0, %1, %2, %3" : "=v"(d) : "v"(a), "v"(b), "v"(c));
  return d;
}
__device__ __forceinline__ void ce32(unsigned int& x, unsigned int& y) {
  unsigned int a = min(x, y), b = max(x, y);
  x = a; y = b;
}

// ================= stage 1 bodies (independent work, fused dispatch) =================
// wcast v2: 8 elems/thread (2x float4 in, 8 bf16 out). 786432 elems = 384 blocks of
// 2048; every array boundary is a multiple of 2048 so each block maps to exactly one
// src/dst pair. blk==384 is the rp-BN fold prep.
__device__ __forceinline__
void wcast_body(const float* Wq, const float* Wkv, const float* Wp,
                const float* W1, const float* W2,
                unsigned short* oQKV, unsigned short* oP,
                unsigned short* o1, unsigned short* o2,
                const float* rp_w1, const float* rp_g, const float* rp_b,
                const float* rp_m, const float* rp_v, const float* rp_w2,
                float4* w1f, float4* W2t, int blk) {
  if (blk == 384) {             // prep: fold rp BN into w1, reduce rp_w2 over heads
    int c = threadIdx.x;
    float s  = rp_g[c] / sqrtf(rp_v[c] + EPSBN);
    float b0 = rp_b[c] - rp_m[c] * s;
    w1f[c] = make_float4(rp_w1[c*3+0]*s, rp_w1[c*3+1]*s, rp_w1[c*3+2]*s, b0);
    float a0=0.f,a1=0.f,a2=0.f,a3=0.f;
    for (int o = 0; o < 64; o++) {
      a0 += rp_w2[(      o)*CC + c];
      a1 += rp_w2[( 64 + o)*CC + c];
      a2 += rp_w2[(128 + o)*CC + c];
      a3 += rp_w2[(192 + o)*CC + c];
    }
    W2t[c] = make_float4(a0,a1,a2,a3);
    return;
  }
  int i0 = blk * 2048 + threadIdx.x * 8;
  const float* src; unsigned short* dst; int di;
  if (i0 < 65536)        { src = Wq  +  i0;           dst = oQKV; di = i0; }
  else if (i0 < 196608)  { src = Wkv + (i0 - 65536);  dst = oQKV; di = i0; }
  else if (i0 < 262144)  { src = Wp  + (i0 - 196608); dst = oP;   di = i0 - 196608; }
  else if (i0 < 524288)  { src = W1  + (i0 - 262144); dst = o1;   di = i0 - 262144; }
  else                   { src = W2  + (i0 - 524288); dst = o2;   di = i0 - 524288; }
  float4 a = ((const float4*)src)[0];
  float4 b = ((const float4*)src)[1];
  unsigned short us[8] = {f2b(a.x), f2b(a.y), f2b(a.z), f2b(a.w),
                          f2b(b.x), f2b(b.y), f2b(b.z), f2b(b.w)};
  *(uint4*)&dst[di] = *(const uint4*)us;
}

__device__ __forceinline__
void xcast_body(const float* x, unsigned short* xb, float* xf,
                float (*T)[65], int bx, int by, int bz) {
  int n0 = bx * 64, c0 = by * 64, bb = bz;
  int tid = threadIdx.x;
  {
    int crow = tid >> 2, ns = (tid & 3) * 16;
    const float* xp = x + ((size_t)(bb*CC + c0 + crow))*NPT + n0 + ns;
#pragma unroll
    for (int i = 0; i < 4; i++) {
      float4 v = ((const float4*)xp)[i];
      T[crow][ns + i*4 + 0] = v.x; T[crow][ns + i*4 + 1] = v.y;
      T[crow][ns + i*4 + 2] = v.z; T[crow][ns + i*4 + 3] = v.w;
    }
  }
  __syncthreads();
  {
    int nrow = tid >> 2, cs = (tid & 3) * 16;
    float vals[16];
#pragma unroll
    for (int i = 0; i < 16; i++) vals[i] = T[cs + i][nrow];
    size_t orow = ((size_t)(bb*NPT + n0 + nrow))*CC + c0 + cs;
#pragma unroll
    for (int i = 0; i < 4; i++)
      *(float4*)&xf[orow + i*4] = make_float4(vals[i*4], vals[i*4+1], vals[i*4+2], vals[i*4+3]);
    unsigned short us[16];
#pragma unroll
    for (int i = 0; i < 16; i++) us[i] = f2b(vals[i]);
    *(uint4*)&xb[orow]     = *(const uint4*)&us[0];
    *(uint4*)&xb[orow + 8] = *(const uint4*)&us[8];
  }
}

// KNN stage 1: packed-u32 sorted-insert via v_med3_u32 — 1 op/position.
// Insertion into ascending list k0..k15 (applied DESCENDING so old k_{i-1} is read):
//   k_i' = med3(key, k_{i-1}, k_i);  k0' = min(key, k0)
// Keys are (non-negative float bits & ~0x1FF) | within-512-chunk index, so u32
// order == (distance, index) order and sentinels 0xFFFFFFFF sort last.
#define MPROC(M4, MI) { \
    float nd = fmaf(qx2, (M4).x, fmaf(qy2, (M4).y, fmaf(qz2, (M4).z, (M4).w + qsq))); \
    nd = fmaxf(nd, 0.f); \
    unsigned int key = (__float_as_uint(nd) & 0xFFFFFE00u) | (unsigned int)(MI); \
    k15 = med3u(key, k14, k15); k14 = med3u(key, k13, k14); \
    k13 = med3u(key, k12, k13); k12 = med3u(key, k11, k12); \
    k11 = med3u(key, k10, k11); k10 = med3u(key, k9,  k10); \
    k9  = med3u(key, k8,  k9 ); k8  = med3u(key, k7,  k8 ); \
    k7  = med3u(key, k6,  k7 ); k6  = med3u(key, k5,  k6 ); \
    k5  = med3u(key, k4,  k5 ); k4  = med3u(key, k3,  k4 ); \
    k3  = med3u(key, k2,  k3 ); k2  = med3u(key, k1,  k2 ); \
    k1  = med3u(key, k0,  k1 ); k0  = min(key, k0); }

// Block stages one 512-pt chunk; each of 4 waves scans a 128-quarter for the same
// 64 queries, then TWO in-LDS butterfly rounds (partner ^1, ^2) collapse the 4
// partial lists into the chunk's true top-16 (u32 keys, same chunk -> same
// tie-break space). Wave 0 writes -> Pp is 8 lists/query = 4 MB.
__device__ __forceinline__
void knn_partial_body(const float* xyz, unsigned int* Pp, char* smem,
                      int s, int qg, int b) {
  float4* sp = (float4*)smem;
  const float* base = xyz + (size_t)b * 3 * NPT;
  int c0 = s * 512;
  for (int i = threadIdx.x; i < 512; i += 256) {
    float mx = base[c0 + i], my = base[NPT + c0 + i], mz = base[2*NPT + c0 + i];
    sp[i] = make_float4(mx, my, mz, mx*mx + my*my + mz*mz);
  }
  int lane = threadIdx.x & 63;
  int wv   = threadIdx.x >> 6;
  int qn   = qg * 64 + lane;
  float qx = base[qn], qy = base[NPT + qn], qz = base[2*NPT + qn];
  float qsq = qx*qx + qy*qy + qz*qz;
  float qx2 = -2.f*qx, qy2 = -2.f*qy, qz2 = -2.f*qz;
  __syncthreads();

  unsigned int k0=0xFFFFFFFFu,k1=0xFFFFFFFFu,k2=0xFFFFFFFFu,k3=0xFFFFFFFFu,
               k4=0xFFFFFFFFu,k5=0xFFFFFFFFu,k6=0xFFFFFFFFu,k7=0xFFFFFFFFu,
               k8=0xFFFFFFFFu,k9=0xFFFFFFFFu,k10=0xFFFFFFFFu,k11=0xFFFFFFFFu,
               k12=0xFFFFFFFFu,k13=0xFFFFFFFFu,k14=0xFFFFFFFFu,k15=0xFFFFFFFFu;

  int sb = wv * 128;            // wave's sub-chunk; payload = within-512 index
  for (int mm = 0; mm < 128; mm += 4) {
    float4 a4 = sp[sb+mm], bq = sp[sb+mm+1], cq = sp[sb+mm+2], dq = sp[sb+mm+3];
    MPROC(a4, sb+mm)
    MPROC(bq, sb+mm+1)
    MPROC(cq, sb+mm+2)
    MPROC(dq, sb+mm+3)
  }

  // ---- in-block merge: 4 sorted 16-lists (same chunk) -> chunk top-16 ----
  unsigned int a[16] = {k0,k1,k2,k3,k4,k5,k6,k7,k8,k9,k10,k11,k12,k13,k14,k15};
  unsigned int* L = (unsigned int*)smem;        // reuses sp space (stride 17: conflict-free)
  int me = (wv*64 + lane)*17;
  __syncthreads();                               // sp reads done
#pragma unroll
  for (int pw = 1; pw <= 2; pw <<= 1) {
#pragma unroll
    for (int i = 0; i < 16; i++) L[me + i] = a[i];
    __syncthreads();
    int pb = ((wv ^ pw)*64 + lane)*17;
    unsigned int t[16];
#pragma unroll
    for (int i = 0; i < 16; i++) t[i] = min(a[i], L[pb + 15 - i]);
#pragma unroll
    for (int d = 8; d >= 1; d >>= 1)
#pragma unroll
      for (int i = 0; i < 16; i++)
        if ((i & d) == 0) ce32(t[i], t[i + d]);
#pragma unroll
    for (int i = 0; i < 16; i++) a[i] = t[i];
    __syncthreads();                             // before next round's L overwrite
  }
  if (wv == 0) {
    int gq = b * NPT + qn;
    uint4* out = (uint4*)(Pp + (size_t)gq * 128 + s * 16);
    out[0] = make_uint4(a[0],  a[1],  a[2],  a[3]);
    out[1] = make_uint4(a[4],  a[5],  a[6],  a[7]);
    out[2] = make_uint4(a[8],  a[9],  a[10], a[11]);
    out[3] = make_uint4(a[12], a[13], a[14], a[15]);
  }
}

// stage1 fused dispatch: [0,1024) knn | [1024,1536) xcast | [1536,1921) wcast.
// knn FIRST so the VALU-bound tail starts at t=0 and the memory-bound cast blocks
// co-schedule under it. LDS pool: max(xcast 16640, knn sp 8192 -> L 17400) = 17408.
__global__ __launch_bounds__(256) __attribute__((amdgpu_waves_per_eu(1, 4)))
void stage1_kernel(const float* x, unsigned short* xb, float* xf,
                   const float* xyz, unsigned int* Pp,
                   const float* Wq, const float* Wkv, const float* Wp,
                   const float* W1, const float* W2,
                   unsigned short* oQKV, unsigned short* oP,
                   unsigned short* o1, unsigned short* o2,
                   const float* rp_w1, const float* rp_g, const float* rp_b,
                   const float* rp_m, const float* rp_v, const float* rp_w2,
                   float4* w1f, float4* W2t) {
  __shared__ __align__(16) char smem[17408];
  int bi = blockIdx.x;
  if (bi < 1024) {
    knn_partial_body(xyz, Pp, smem, bi & 7, (bi >> 3) & 63, bi >> 9);
  } else if (bi < 1536) {
    int i = bi - 1024;
    xcast_body(x, xb, xf, (float(*)[65])smem, i & 63, (i >> 6) & 3, i >> 8);
  } else {
    wcast_body(Wq, Wkv, Wp, W1, W2, oQKV, oP, o1, o2,
               rp_w1, rp_g, rp_b, rp_m, rp_v, rp_w2, w1f, W2t, bi - 1536);
  }
}

// ================= stage 2: qkv GEMM + knn_merge (independent, fused) ================
// Merge v3: lane = (query, chunk) — 8 queries/wave, each query's 8 sorted chunk-
// lists live in 8 adjacent lanes (16 entries each, 64B coalesced load). 3 butterfly
// rounds m=1,2,4 of "lowest-16 of two sorted-16s" (u64 keys = maskedDist<<32|gidx
// for exact global tie-break), bitonic re-sort except last round (set suffices:
// downstream softmax+sum is permutation-invariant, bias pairs with its own idx).
__device__ __forceinline__ unsigned long long min64(unsigned long long a, unsigned long long b) {
  return a < b ? a : b;
}
__device__ __forceinline__ void ce64(unsigned long long& x, unsigned long long& y) {
  unsigned long long a = x, b = y;
  bool lt = a < b;
  x = lt ? a : b;
  y = lt ? b : a;
}
__device__ __forceinline__
void knn_merge_body(const unsigned int* Pp, int* idx_out, int blk) {
  int wv   = threadIdx.x >> 6;
  int lane = threadIdx.x & 63;
  int gq   = (blk*4 + wv)*8 + (lane >> 3);
  int s    = lane & 7;
  const uint4* src = (const uint4*)(Pp + (size_t)gq * 128 + s * 16);
  uint4 u0 = src[0], u1 = src[1], u2 = src[2], u3 = src[3];
  unsigned int gb = (unsigned int)s * 512u;
  unsigned long long a[16];
  {
    unsigned int ks[16] = {u0.x,u0.y,u0.z,u0.w, u1.x,u1.y,u1.z,u1.w,
                           u2.x,u2.y,u2.z,u2.w, u3.x,u3.y,u3.z,u3.w};
#pragma unroll
    for (int t = 0; t < 16; t++)
      a[t] = ((unsigned long long)(ks[t] & 0xFFFFFE00u) << 32) | (gb + (ks[t] & 0x1FFu));
  }
#pragma unroll
  for (int r = 0; r < 3; r++) {
    const int m = 1 << r;
    unsigned long long t[16];
#pragma unroll
    for (int i = 0; i < 16; i++) {
      unsigned long long pb = __shfl_xor(a[15 - i], m, 64);
      t[i] = min64(a[i], pb);
    }
    if (r < 2) {
#pragma unroll
      for (int d = 8; d >= 1; d >>= 1)
#pragma unroll
        for (int i = 0; i < 16; i++)
          if ((i & d) == 0) ce64(t[i], t[i + d]);
    }
#pragma unroll
    for (int i = 0; i < 16; i++) a[i] = t[i];
  }
  if (s == 0) {
    int4* o = (int4*)(idx_out + gq*16);
    o[0] = make_int4((int)(unsigned)a[0],  (int)(unsigned)a[1],
                     (int)(unsigned)a[2],  (int)(unsigned)a[3]);
    o[1] = make_int4((int)(unsigned)a[4],  (int)(unsigned)a[5],
                     (int)(unsigned)a[6],  (int)(unsigned)a[7]);
    o[2] = make_int4((int)(unsigned)a[8],  (int)(unsigned)a[9],
                     (int)(unsigned)a[10], (int)(unsigned)a[11]);
    o[3] = make_int4((int)(unsigned)a[12], (int)(unsigned)a[13],
                     (int)(unsigned)a[14], (int)(unsigned)a[15]);
  }
}

// ------- MFMA bf16 GEMM v3: NT-templated N-tile (NT*64 rows) ------------------------
struct MG {
  const unsigned short* A; const unsigned short* Wt; int K; int M;
  unsigned short* OutB; float* OutF;
  const float* bias; const float* resid;
  const float* bng; const float* bnb; const float* bnm; const float* bnv;
};

template<int EPI, int NT>
__device__ __forceinline__ void mgemm_body(const MG& p, int bx, int by, int bz) {
  __shared__ unsigned short As[NT*64*64];
  __shared__ unsigned short Bs[64*64];
  const int tid  = threadIdx.x;
  const int bb   = bz;
  const int n0   = bx * (NT*64);
  const int m0   = by * 64;
  const int lane = tid & 63;
  const int wv   = tid >> 6;
  const int l15  = lane & 15;
  const int quad = lane >> 4;
  const int K    = p.K;
  const int WR   = NT*16;                   // wave row span

  f32x4 acc[NT][4];
#pragma unroll
  for (int i = 0; i < NT; i++)
#pragma unroll
    for (int j = 0; j < 4; j++) acc[i][j] = (f32x4){0.f, 0.f, 0.f, 0.f};

  const int srow = wv*8 + (lane >> 3);
  const int pseg = lane & 7;
  const unsigned short* Abase = p.A  + (size_t)bb*NPT*K;

  for (int c0 = 0; c0 < K; c0 += 64) {
#pragma unroll
    for (int t = 0; t < NT*2; t++) {
      int row = t*32 + srow;
      int ls  = pseg ^ (row & 7);
      gl_lds16(Abase + (size_t)(n0 + row)*K + c0 + ls*8,
               &As[wv*512 + t*2048 + lane*8]);
    }
#pragma unroll
    for (int t = 0; t < 2; t++) {
      int row = t*32 + srow;
      int ls  = pseg ^ (row & 7);
      gl_lds16(p.Wt + (size_t)(m0 + row)*K + c0 + ls*8,
               &Bs[wv*512 + t*2048 + lane*8]);
    }
    __syncthreads();
    short8 bf[4][2];
#pragma unroll
    for (int mt = 0; mt < 4; mt++)
#pragma unroll
      for (int kk = 0; kk < 2; kk++) {
        int row = mt*16 + l15;
        int ps  = (kk*4 + quad) ^ (row & 7);
        bf[mt][kk] = *(const short8*)&Bs[row*64 + ps*8];
      }
#pragma unroll
    for (int nt = 0; nt < NT; nt++)
#pragma unroll
      for (int kk = 0; kk < 2; kk++) {
        int row = wv*WR + nt*16 + l15;
        int ps  = (kk*4 + quad) ^ (row & 7);
        short8 af = *(const short8*)&As[row*64 + ps*8];
#pragma unroll
        for (int mt = 0; mt < 4; mt++)
          acc[nt][mt] = __builtin_amdgcn_mfma_f32_16x16x32_bf16(af, bf[mt][kk], acc[nt][mt], 0, 0, 0);
      }
    __syncthreads();
  }

  if (EPI == 0 || EPI == 1) {
    float bs[4];
#pragma unroll
    for (int mt = 0; mt < 4; mt++)
      bs[mt] = (EPI == 1) ? p.bias[m0 + mt*16 + l15] : 0.f;
#pragma unroll
    for (int nt = 0; nt < NT; nt++)
#pragma unroll
      for (int reg = 0; reg < 4; reg++) {
        size_t row = ((size_t)(bb*NPT + n0 + wv*WR + nt*16 + quad*4 + reg))*p.M + m0;
#pragma unroll
        for (int mt = 0; mt < 4; mt++) {
          float v = acc[nt][mt][reg] + bs[mt];
          if (EPI == 1) v = fmaxf(v, 0.f);
          p.OutB[row + mt*16 + l15] = f2b(v);
        }
      }
  } else if (EPI == 2) {
    float sc[4], sh[4];
#pragma unroll
    for (int mt = 0; mt < 4; mt++) {
      int m = m0 + mt*16 + l15;
      float s = p.bng[m] / sqrtf(p.bnv[m] + EPSBN);
      sc[mt] = s; sh[mt] = p.bnb[m] - p.bnm[m]*s;
    }
#pragma unroll
    for (int nt = 0; nt < NT; nt++)
#pragma unroll
      for (int reg = 0; reg < 4; reg++) {
        size_t row = ((size_t)(bb*NPT + n0 + wv*WR + nt*16 + quad*4 + reg))*p.M + m0;
#pragma unroll
        for (int mt = 0; mt < 4; mt++) {
          float r = p.resid[row + mt*16 + l15];
          float v = (acc[nt][mt][reg] + r)*sc[mt] + sh[mt];
          p.OutF[row + mt*16 + l15] = v;
          p.OutB[row + mt*16 + l15] = f2b(v);
        }
      }
  } else {  // EPI == 3
    __shared__ float Tb[4][4][16*17];
    float sc[4], sh[4], bs[4];
#pragma unroll
    for (int mt = 0; mt < 4; mt++) {
      int m = m0 + mt*16 + l15;
      float s = p.bng[m] / sqrtf(p.bnv[m] + EPSBN);
      sc[mt] = s; sh[mt] = p.bnb[m] - p.bnm[m]*s;
      bs[mt] = p.bias[m];
    }
#pragma unroll
    for (int nt = 0; nt < NT; nt++) {
#pragma unroll
      for (int reg = 0; reg < 4; reg++) {
        size_t row = ((size_t)(bb*NPT + n0 + wv*WR + nt*16 + quad*4 + reg))*p.M + m0;
#pragma unroll
        for (int mt = 0; mt < 4; mt++) {
          float r = p.resid[row + mt*16 + l15];
          float v = (acc[nt][mt][reg] + bs[mt] + r)*sc[mt] + sh[mt];
          Tb[wv][mt][(quad*4 + reg)*17 + l15] = v;
        }
      }
      __syncthreads();
#pragma unroll
      for (int mt = 0; mt < 4; mt++)
#pragma unroll
        for (int reg = 0; reg < 4; reg++) {
          float v = Tb[wv][mt][l15*17 + quad*4 + reg];
          p.OutF[((size_t)(bb*p.M + m0 + mt*16 + quad*4 + reg))*NPT
                 + n0 + wv*WR + nt*16 + l15] = v;
        }
      __syncthreads();
    }
  }
}

template<int EPI, int NT>
__global__ __launch_bounds__(256)
void mgemm_kernel(MG p) { mgemm_body<EPI, NT>(p, blockIdx.x, blockIdx.y, blockIdx.z); }

// stage2 fused: [0,768) qkv GEMM (long poles first) | [768,1024) knn_merge
__global__ __launch_bounds__(256)
void stage2_kernel(const unsigned int* Pp, int* idx, MG pqkv) {
  int bi = blockIdx.x;
  if (bi < 768) {
    mgemm_body<0, 2>(pqkv, bi & 31, (bi >> 5) % 12, bi / 384);
  } else {
    knn_merge_body(Pp, idx, bi - 768);
  }
}

// ---------------- fused attention v5: barrier-free point loop --------------------
// red[wv] is WAVE-PRIVATE: writers and readers are the same wave, and DS ops from
// one wave execute in order (compiler inserts lgkmcnt for the RAW) — so the two
// per-point __syncthreads were pure overhead (8 block-wide drains/block). Removed;
// the 4-point loop now pipelines gathers across points.
__global__ __launch_bounds__(256, 4)
void attn_kernel(const unsigned short* __restrict__ qkv, const float4* __restrict__ w1f,
                 const float4* __restrict__ W2t, const float* __restrict__ xyz,
                 const int* __restrict__ idx, unsigned short* __restrict__ attn_b) {
  __shared__ float4 sw1[256];
  __shared__ float4 sw2[256];
  __shared__ int   sidx[4][16];
  __shared__ float srel[4][16][4];
  __shared__ float sbias[4][16][4];
  __shared__ float red[4][16*68];
  int tid = threadIdx.x;
  int bn0 = blockIdx.x * 4;
  int b   = bn0 >> 12;
  sw1[tid] = w1f[tid];
  sw2[tid] = W2t[tid];
  if (tid < 64) {
    int p = tid >> 4, kk = tid & 15;
    int bn = bn0 + p, n = bn & 4095;
    int j = idx[bn*16 + kk];
    sidx[p][kk] = j;
    const float* pb = xyz + (size_t)b * 3 * NPT;
    srel[p][kk][0] = pb[j]         - pb[n];
    srel[p][kk][1] = pb[NPT + j]   - pb[NPT + n];
    srel[p][kk][2] = pb[2*NPT + j] - pb[2*NPT + n];
  }
  __syncthreads();
  {  // ---- bias phase: 4 points per weight read ----
    int kk = tid >> 4, cs = tid & 15;
    float rx[4], ry[4], rz[4], h[4][4];
#pragma unroll
    for (int p = 0; p < 4; p++) {
      rx[p] = srel[p][kk][0]; ry[p] = srel[p][kk][1]; rz[p] = srel[p][kk][2];
#pragma unroll
      for (int q = 0; q < 4; q++) h[p][q] = 0.f;
    }
#pragma unroll
    for (int i = 0; i < 16; i++) {
      int c = cs*16 + ((i + cs) & 15);
      float4 w  = sw1[c];
      float4 w2 = sw2[c];
#pragma unroll
      for (int p = 0; p < 4; p++) {
        float t0 = fmaxf(fmaf(rx[p], w.x, fmaf(ry[p], w.y, fmaf(rz[p], w.z, w.w))), 0.f);
        h[p][0] = fmaf(t0, w2.x, h[p][0]); h[p][1] = fmaf(t0, w2.y, h[p][1]);
        h[p][2] = fmaf(t0, w2.z, h[p][2]); h[p][3] = fmaf(t0, w2.w, h[p][3]);
      }
    }
#pragma unroll
    for (int off = 1; off < 16; off <<= 1)
#pragma unroll
      for (int p = 0; p < 4; p++)
#pragma unroll
        for (int q = 0; q < 4; q++)
          h[p][q] += __shfl_xor(h[p][q], off, 64);
    if (cs == 0)
#pragma unroll
      for (int p = 0; p < 4; p++)
#pragma unroll
        for (int q = 0; q < 4; q++) sbias[p][kk][q] = h[p][q];
  }
  __syncthreads();
  // ---- attention phase: 4 points, barrier-free (red[wv] is wave-private) ----
  int wv   = tid >> 6;
  int lane = tid & 63;
  int k    = lane >> 2;
  int c4   = lane & 3;
  int ch0  = wv*64 + c4*16;
  size_t base = (size_t)(b*NPT) * 768;
#pragma unroll 1
  for (int p = 0; p < 4; p++) {
    int bn = bn0 + p;
    size_t rowq = (size_t)bn * 768;
    float qf[16];
    {
      uint4 q0 = *(const uint4*)(qkv + rowq + ch0);
      uint4 q1 = *(const uint4*)(qkv + rowq + ch0 + 8);
      up16(q0, q1, qf);
    }
    int j = sidx[p][k];
    float dot = 0.f;
    {
      const unsigned short* krow = qkv + base + (size_t)j*768 + 256 + ch0;
      uint4 k0 = *(const uint4*)(krow);
      uint4 k1 = *(const uint4*)(krow + 8);
      float kf[16];
      up16(k0, k1, kf);
#pragma unroll
      for (int i = 0; i < 16; i++) dot = fmaf(qf[i], kf[i], dot);
    }
    dot += __shfl_xor(dot, 1, 64);
    dot += __shfl_xor(dot, 2, 64);
    float logit = dot * 0.125f + sbias[p][k][wv];
    float mx = logit;
#pragma unroll
    for (int off = 4; off < 64; off <<= 1) mx = fmaxf(mx, __shfl_xor(mx, off, 64));
    float e = __expf(logit - mx);
    float ssum = e;
#pragma unroll
    for (int off = 4; off < 64; off <<= 1) ssum += __shfl_xor(ssum, off, 64);
    float w = e / ssum;
    {
      const unsigned short* vrow = qkv + base + (size_t)j*768 + 512 + ch0;
      uint4 v0 = *(const uint4*)(vrow);
      uint4 v1 = *(const uint4*)(vrow + 8);
      float vf[16];
      up16(v0, v1, vf);
      float* dst = &red[wv][k*68 + c4*16];
#pragma unroll
      for (int g = 0; g < 4; g++)
        ((float4*)dst)[g] = make_float4(w*vf[g*4], w*vf[g*4+1], w*vf[g*4+2], w*vf[g*4+3]);
    }
    float o = 0.f;
#pragma unroll
    for (int kk2 = 0; kk2 < 16; kk2++) o += red[wv][kk2*68 + lane];
    attn_b[(size_t)bn*256 + wv*64 + lane] = f2b(o);
  }
}

extern "C" void kernel_launch(void* const* d_in, const int* in_sizes, int n_in,
                              void* d_out, int out_size, void* d_ws, size_t ws_size,
                              hipStream_t stream) {
  const float* x     = (const float*)d_in[0];
  const float* xyz   = (const float*)d_in[1];
  const float* Wq    = (const float*)d_in[2];
  const float* Wkv   = (const float*)d_in[3];
  const float* Wproj = (const float*)d_in[4];
  const float* rp_w1 = (const float*)d_in[5];
  const float* rp_g  = (const float*)d_in[6];
  const float* rp_b  = (const float*)d_in[7];
  const float* rp_m  = (const float*)d_in[8];
  const float* rp_v  = (const float*)d_in[9];
  const float* rp_w2 = (const float*)d_in[10];
  const float* bn1_g = (const float*)d_in[11];
  const float* bn1_b = (const float*)d_in[12];
  const float* bn1_m = (const float*)d_in[13];
  const float* bn1_v = (const float*)d_in[14];
  const float* bn2_g = (const float*)d_in[15];
  const float* bn2_b = (const float*)d_in[16];
  const float* bn2_m = (const float*)d_in[17];
  const float* bn2_v = (const float*)d_in[18];
  const float* ffn_w1 = (const float*)d_in[19];
  const float* ffn_b1 = (const float*)d_in[20];
  const float* ffn_w2 = (const float*)d_in[21];
  const float* ffn_b2 = (const float*)d_in[22];

  char* ws = (char*)d_ws;
  // static region
  float4* w1f = (float4*)(ws + 0);                         //   4 KB
  float4* W2t = (float4*)(ws + 4096);                      //   4 KB
  int*    idx = (int*)  (ws + 8192);                       // 512 KB
  // reuse region A (32 MB): KNN scratch first, then post-attn tensors
  const size_t oA = 532480;
  unsigned int*   Pp     = (unsigned int*)(ws + oA);       // 4 MB u32 [B*N][128] keys
  unsigned short* attn_b = (unsigned short*)(ws + oA);                 //  4 MB bf16 [B][N][256]
  float*          x1f    = (float*)(ws + oA + (4u<<20));               //  8 MB fp32 [B][N][256]
  unsigned short* x1b    = (unsigned short*)(ws + oA + (12u<<20));     //  4 MB bf16 [B][N][256]
  unsigned short* h_b    = (unsigned short*)(ws + oA + (16u<<20));     // 16 MB bf16 [B][N][1024]
  // region B: weights + casted x + qkv
  const size_t oB = oA + (32u<<20);
  unsigned short* Wqkv_b  = (unsigned short*)(ws + oB);                // 384 KB [768][256]
  unsigned short* Wproj_b = (unsigned short*)(ws + oB + 393216);       // 128 KB
  unsigned short* W1_b    = (unsigned short*)(ws + oB + 524288);       // 512 KB
  unsigned short* W2_b    = (unsigned short*)(ws + oB + 1048576);      // 512 KB
  unsigned short* xb      = (unsigned short*)(ws + oB + 1572864);      //   4 MB bf16 [B][N][256]
  float*          xf      = (float*)(ws + oB + 1572864 + (4u<<20));    //   8 MB fp32 [B][N][256]
  unsigned short* qkv     = (unsigned short*)(ws + oB + 1572864 + (12u<<20)); // 12 MB bf16 [B][N][768]

  stage1_kernel<<<1921, 256, 0, stream>>>(x, xb, xf, xyz, Pp,
                                          Wq, Wkv, Wproj, ffn_w1, ffn_w2,
                                          Wqkv_b, Wproj_b, W1_b, W2_b,
                                          rp_w1, rp_g, rp_b, rp_m, rp_v, rp_w2,
                                          w1f, W2t);

  MG pqkv = {xb, Wqkv_b, 256, 768, qkv, nullptr,
             nullptr, nullptr, nullptr, nullptr, nullptr, nullptr};
  stage2_kernel<<<1024, 256, 0, stream>>>(Pp, idx, pqkv);

  attn_kernel<<<(BB*NPT)/4, 256, 0, stream>>>(qkv, w1f, W2t, xyz, idx, attn_b);

  MG pproj = {attn_b, Wproj_b, 256, 256, x1b, x1f,
              nullptr, xf, bn1_g, bn1_b, bn1_m, bn1_v};
  mgemm_kernel<2, 1><<<dim3(64, 4, BB), 256, 0, stream>>>(pproj);

  MG pf1 = {x1b, W1_b, 256, 1024, h_b, nullptr,
            ffn_b1, nullptr, nullptr, nullptr, nullptr, nullptr};
  mgemm_kernel<1, 2><<<dim3(32, 16, BB), 256, 0, stream>>>(pf1);

  MG pf2 = {h_b, W2_b, 1024, 256, nullptr, (float*)d_out,
            ffn_b2, x1f, bn2_g, bn2_b, bn2_m, bn2_v};
  mgemm_kernel<3, 1><<<dim3(64, 4, BB), 256, 0, stream>>>(pf2);
}